// Round 1
// baseline (324.236 us; speedup 1.0000x reference)
//
#include <hip/hip_runtime.h>
#include <hip/hip_bf16.h>
#include <stdint.h>

// ---------------------------------------------------------------------------
// RoPE self-attention, B=2 L=2048 D=1024 H=16 Dh=64, f32 in/out, bf16 MFMA core
// ---------------------------------------------------------------------------

typedef __attribute__((ext_vector_type(8))) short short8;
typedef __attribute__((ext_vector_type(4))) float floatx4;

#define BDIM 2
#define LDIM 2048
#define DDIM 1024
#define HDIM 16
#define DH 64
#define ML (BDIM * LDIM)   // 4096 rows

// f32 -> bf16 round-to-nearest-even
__device__ __forceinline__ uint16_t f2b(float x) {
  uint32_t b = __float_as_uint(x);
  b += 0x7FFFu + ((b >> 16) & 1u);
  return (uint16_t)(b >> 16);
}

__device__ __forceinline__ void load_lds_16B(const uint16_t* g, uint16_t* l) {
  __builtin_amdgcn_global_load_lds(
      (const __attribute__((address_space(1))) void*)g,
      (__attribute__((address_space(3))) void*)l, 16, 0, 0);
}

// ---------------- convert f32 -> bf16, 4 elems/thread ----------------------
__global__ void cvt_bf16_x4(const float* __restrict__ in, uint16_t* __restrict__ out, int n4) {
  int i = blockIdx.x * 256 + threadIdx.x;
  if (i >= n4) return;
  float4 v = ((const float4*)in)[i];
  uint32_t lo = (uint32_t)f2b(v.x) | ((uint32_t)f2b(v.y) << 16);
  uint32_t hi = (uint32_t)f2b(v.z) | ((uint32_t)f2b(v.w) << 16);
  ((uint2*)out)[i] = make_uint2(lo, hi);
}

// ---------------- rope cos/sin table: [L][32] ------------------------------
__global__ void rope_table(float* __restrict__ cosT, float* __restrict__ sinT) {
  int i = blockIdx.x * 256 + threadIdx.x;  // L*32 = 65536
  int l = i >> 5, f = i & 31;
  // invfreq = 10000^(-f/32) = 2^(-f * log2(10000)/32)
  float invf = exp2f(-(float)f * (13.287712379549449f / 32.f));
  float ang = (float)l * invf;
  cosT[i] = cosf(ang);
  sinT[i] = sinf(ang);
}

// ---------------- GEMM (bt): C[m][n] = sum_k A[m][k]*B[n][k] ---------------
// A: MxK bf16 row-major, B: NxK bf16 row-major, C: MxN f32.
// 128x128 tile, BK=32, 256 threads = 4 waves (2x2), each wave 64x64 (4x4 frags)
__global__ __launch_bounds__(256) void gemm_bt(const uint16_t* __restrict__ A,
                                               const uint16_t* __restrict__ B,
                                               float* __restrict__ C,
                                               int M, int N, int K) {
  __shared__ uint16_t As[128 * 32];
  __shared__ uint16_t Bs[128 * 32];
  const int m0 = blockIdx.x * 128;
  const int n0 = blockIdx.y * 128;
  const int t = threadIdx.x;
  const int lane = t & 63;
  const int w = t >> 6;
  const int wr = w >> 1, wc = w & 1;
  const int srow = t >> 2;            // staging row (0..63)
  const int scol = (t & 3) * 8;       // staging col elem
  const int c0 = lane & 15, c1 = lane >> 4;

  floatx4 acc[4][4];
#pragma unroll
  for (int i = 0; i < 4; ++i)
#pragma unroll
    for (int j = 0; j < 4; ++j) acc[i][j] = (floatx4){0.f, 0.f, 0.f, 0.f};

  for (int k0 = 0; k0 < K; k0 += 32) {
    const uint16_t* ga = A + (size_t)(m0 + srow) * K + k0 + scol;
    load_lds_16B(ga, &As[t * 8]);
    load_lds_16B(ga + (size_t)64 * K, &As[t * 8 + 64 * 32]);
    const uint16_t* gb = B + (size_t)(n0 + srow) * K + k0 + scol;
    load_lds_16B(gb, &Bs[t * 8]);
    load_lds_16B(gb + (size_t)64 * K, &Bs[t * 8 + 64 * 32]);
    __syncthreads();

    short8 a[4], b[4];
#pragma unroll
    for (int i = 0; i < 4; ++i)
      a[i] = *(const short8*)&As[(wr * 64 + i * 16 + c0) * 32 + c1 * 8];
#pragma unroll
    for (int j = 0; j < 4; ++j)
      b[j] = *(const short8*)&Bs[(wc * 64 + j * 16 + c0) * 32 + c1 * 8];
#pragma unroll
    for (int i = 0; i < 4; ++i)
#pragma unroll
      for (int j = 0; j < 4; ++j)
        acc[i][j] = __builtin_amdgcn_mfma_f32_16x16x32_bf16(a[i], b[j], acc[i][j], 0, 0, 0);
    __syncthreads();
  }

#pragma unroll
  for (int i = 0; i < 4; ++i)
#pragma unroll
    for (int j = 0; j < 4; ++j) {
      int row = m0 + wr * 64 + i * 16 + c1 * 4;
      int col = n0 + wc * 64 + j * 16 + c0;
      float* cp = C + (size_t)row * N + col;
#pragma unroll
      for (int r = 0; r < 4; ++r) cp[(size_t)r * N] = acc[i][j][r];
    }
}

// ---------------- RoPE apply: qkv f32 -> qr, kr bf16 (b,h,l,dh) ------------
__global__ void rope_apply(const float* __restrict__ qkv,
                           const float* __restrict__ cosT,
                           const float* __restrict__ sinT,
                           uint16_t* __restrict__ qr, uint16_t* __restrict__ kr) {
  int idx = blockIdx.x * 256 + threadIdx.x;  // 0 .. ML*DDIM-1
  int m = idx >> 10;        // b*L + l
  int e = idx & 1023;       // position within D
  int h = e >> 6, dh = e & 63;
  int l = m & (LDIM - 1), b = m >> 11;
  int f = dh & 31;
  float c = cosT[l * 32 + f], s = sinT[l * 32 + f];
  size_t base = (size_t)m * (3 * DDIM);
  float q = qkv[base + e];
  float k = qkv[base + DDIM + e];
  int other = (e & ~63) | ((dh < 32) ? dh + 32 : dh - 32);
  float qo = qkv[base + other];
  float ko = qkv[base + DDIM + other];
  float sgn = (dh < 32) ? -1.f : 1.f;
  float qq = q * c + sgn * qo * s;
  float kk = k * c + sgn * ko * s;
  size_t o = ((size_t)((b * HDIM + h) * LDIM + l)) * DH + dh;
  qr[o] = f2b(qq);
  kr[o] = f2b(kk);
}

// ---------------- V transpose: qkv v-part -> vT bf16 (b,h,dh,L) ------------
__global__ void v_transpose(const float* __restrict__ qkv, uint16_t* __restrict__ vT) {
  __shared__ float tile[64][65];
  int b = blockIdx.z, h = blockIdx.y, l0 = blockIdx.x * 64;
  int tx = threadIdx.x & 63, ty = threadIdx.x >> 6;
#pragma unroll
  for (int rr = 0; rr < 16; ++rr) {
    int row = rr * 4 + ty;  // l offset
    tile[row][tx] = qkv[((size_t)(b * LDIM + l0 + row)) * (3 * DDIM) + 2 * DDIM + h * DH + tx];
  }
  __syncthreads();
#pragma unroll
  for (int rr = 0; rr < 16; ++rr) {
    int drow = rr * 4 + ty;  // dh
    vT[((size_t)((b * HDIM + h) * DH + drow)) * LDIM + l0 + tx] = f2b(tile[tx][drow]);
  }
}

// ---------------- flash attention ------------------------------------------
// grid (L/64, H, B), 256 threads = 4 waves, each wave owns 16 q-rows.
// No __syncthreads: all LDS is per-wave.
__global__ __launch_bounds__(256) void attn(const uint16_t* __restrict__ qr,
                                            const uint16_t* __restrict__ kr,
                                            const uint16_t* __restrict__ vT,
                                            uint16_t* __restrict__ out) {
  __shared__ uint16_t Plds[4][16 * 72];  // per-wave P: 16 q rows x (64 kv + 8 pad)
  const int t = threadIdx.x, lane = t & 63, w = t >> 6;
  const int b = blockIdx.z, h = blockIdx.y;
  const int bh = b * HDIM + h;
  const int l0 = blockIdx.x * 64 + w * 16;
  const int c0 = lane & 15, c1 = lane >> 4;
  const uint16_t* Q = qr + (size_t)bh * LDIM * DH;
  const uint16_t* Kp = kr + (size_t)bh * LDIM * DH;
  const uint16_t* Vp = vT + (size_t)bh * DH * LDIM;
  uint16_t* pl = &Plds[w][0];

  short8 qf[2];
  qf[0] = *(const short8*)&Q[(size_t)(l0 + c0) * DH + c1 * 8];
  qf[1] = *(const short8*)&Q[(size_t)(l0 + c0) * DH + 32 + c1 * 8];

  float m[4], lsum[4];
  floatx4 accO[4];
#pragma unroll
  for (int r = 0; r < 4; ++r) { m[r] = -1e30f; lsum[r] = 0.f; }
#pragma unroll
  for (int nt = 0; nt < 4; ++nt) accO[nt] = (floatx4){0.f, 0.f, 0.f, 0.f};

  for (int kv0 = 0; kv0 < LDIM; kv0 += 64) {
    // ---- S = Q K^T (16 x 64), scaled ----
    floatx4 s[4];
#pragma unroll
    for (int nt = 0; nt < 4; ++nt) {
      floatx4 z = (floatx4){0.f, 0.f, 0.f, 0.f};
      const uint16_t* kb = &Kp[(size_t)(kv0 + nt * 16 + c0) * DH + c1 * 8];
      short8 kf0 = *(const short8*)kb;
      short8 kf1 = *(const short8*)(kb + 32);
      z = __builtin_amdgcn_mfma_f32_16x16x32_bf16(qf[0], kf0, z, 0, 0, 0);
      z = __builtin_amdgcn_mfma_f32_16x16x32_bf16(qf[1], kf1, z, 0, 0, 0);
      s[nt] = z * 0.125f;
    }
    // ---- online softmax (rows live on 16 lanes sharing c1) ----
    float tmax[4];
#pragma unroll
    for (int r = 0; r < 4; ++r)
      tmax[r] = fmaxf(fmaxf(s[0][r], s[1][r]), fmaxf(s[2][r], s[3][r]));
#pragma unroll
    for (int mk = 1; mk < 16; mk <<= 1)
#pragma unroll
      for (int r = 0; r < 4; ++r)
        tmax[r] = fmaxf(tmax[r], __shfl_xor(tmax[r], mk));
    float scl[4];
#pragma unroll
    for (int r = 0; r < 4; ++r) {
      float mn = fmaxf(m[r], tmax[r]);
      scl[r] = __expf(m[r] - mn);
      m[r] = mn;
    }
    float ts[4] = {0.f, 0.f, 0.f, 0.f};
#pragma unroll
    for (int nt = 0; nt < 4; ++nt) {
#pragma unroll
      for (int r = 0; r < 4; ++r) {
        float e = __expf(s[nt][r] - m[r]);
        ts[r] += e;
        pl[(c1 * 4 + r) * 72 + nt * 16 + c0] = f2b(e);
      }
    }
#pragma unroll
    for (int mk = 1; mk < 16; mk <<= 1)
#pragma unroll
      for (int r = 0; r < 4; ++r)
        ts[r] += __shfl_xor(ts[r], mk);
#pragma unroll
    for (int r = 0; r < 4; ++r) lsum[r] = lsum[r] * scl[r] + ts[r];
#pragma unroll
    for (int nt = 0; nt < 4; ++nt)
#pragma unroll
      for (int r = 0; r < 4; ++r) accO[nt][r] *= scl[r];

    // ---- O += P V : P from per-wave LDS (layout-convert), V^T from global ----
    short8 pa0 = *(const short8*)&pl[c0 * 72 + c1 * 8];
    short8 pa1 = *(const short8*)&pl[c0 * 72 + 32 + c1 * 8];
#pragma unroll
    for (int nt = 0; nt < 4; ++nt) {
      const uint16_t* vb = &Vp[(size_t)(nt * 16 + c0) * LDIM + kv0 + c1 * 8];
      short8 vf0 = *(const short8*)vb;
      short8 vf1 = *(const short8*)(vb + 32);
      accO[nt] = __builtin_amdgcn_mfma_f32_16x16x32_bf16(pa0, vf0, accO[nt], 0, 0, 0);
      accO[nt] = __builtin_amdgcn_mfma_f32_16x16x32_bf16(pa1, vf1, accO[nt], 0, 0, 0);
    }
  }

  // ---- finalize: divide by lsum, write attn_out (b,l,D) bf16 ----
  float inv[4];
#pragma unroll
  for (int r = 0; r < 4; ++r) inv[r] = 1.f / lsum[r];
#pragma unroll
  for (int nt = 0; nt < 4; ++nt)
#pragma unroll
    for (int r = 0; r < 4; ++r) {
      float o = accO[nt][r] * inv[r];
      size_t row = (size_t)(b * LDIM + blockIdx.x * 64 + w * 16 + c1 * 4 + r);
      out[row * DDIM + h * DH + nt * 16 + c0] = f2b(o);
    }
}

// ---------------- workspace layout -----------------------------------------
static constexpr size_t OFF_XB    = 0;                    //  8 MB bf16 x
static constexpr size_t OFF_WQKVB = (size_t)8 << 20;      //  6 MB bf16 w_qkv
static constexpr size_t OFF_WOUTB = (size_t)14 << 20;     //  2 MB bf16 w_out
static constexpr size_t OFF_QKV   = (size_t)16 << 20;     // 48 MB f32 qkv
static constexpr size_t OFF_QR    = (size_t)64 << 20;     //  8 MB bf16
static constexpr size_t OFF_KR    = (size_t)72 << 20;     //  8 MB bf16
static constexpr size_t OFF_VT    = (size_t)80 << 20;     //  8 MB bf16
static constexpr size_t OFF_AO    = (size_t)88 << 20;     //  8 MB bf16 attn out
static constexpr size_t OFF_COS   = (size_t)96 << 20;     // 256 KB f32
static constexpr size_t OFF_SIN   = OFF_COS + ((size_t)256 << 10);

extern "C" void kernel_launch(void* const* d_in, const int* in_sizes, int n_in,
                              void* d_out, int out_size, void* d_ws, size_t ws_size,
                              hipStream_t stream) {
  const float* x     = (const float*)d_in[0];
  const float* w_qkv = (const float*)d_in[1];
  const float* w_out = (const float*)d_in[2];
  float* out = (float*)d_out;
  char* ws = (char*)d_ws;

  uint16_t* xb    = (uint16_t*)(ws + OFF_XB);
  uint16_t* wqkvb = (uint16_t*)(ws + OFF_WQKVB);
  uint16_t* woutb = (uint16_t*)(ws + OFF_WOUTB);
  float*    qkv   = (float*)(ws + OFF_QKV);
  uint16_t* qr    = (uint16_t*)(ws + OFF_QR);
  uint16_t* kr    = (uint16_t*)(ws + OFF_KR);
  uint16_t* vT    = (uint16_t*)(ws + OFF_VT);
  uint16_t* ao    = (uint16_t*)(ws + OFF_AO);
  float*    cosT  = (float*)(ws + OFF_COS);
  float*    sinT  = (float*)(ws + OFF_SIN);

  // converts
  cvt_bf16_x4<<<(ML * DDIM / 4 + 255) / 256, 256, 0, stream>>>(x, xb, ML * DDIM / 4);
  cvt_bf16_x4<<<(3 * DDIM * DDIM / 4 + 255) / 256, 256, 0, stream>>>(w_qkv, wqkvb, 3 * DDIM * DDIM / 4);
  cvt_bf16_x4<<<(DDIM * DDIM / 4 + 255) / 256, 256, 0, stream>>>(w_out, woutb, DDIM * DDIM / 4);
  rope_table<<<(LDIM * 32) / 256, 256, 0, stream>>>(cosT, sinT);

  // qkv projection: (4096x1024) x (3072x1024)^T
  gemm_bt<<<dim3(ML / 128, 3 * DDIM / 128), 256, 0, stream>>>(xb, wqkvb, qkv, ML, 3 * DDIM, DDIM);

  // rope + reshapes
  rope_apply<<<(ML * DDIM) / 256, 256, 0, stream>>>(qkv, cosT, sinT, qr, kr);
  v_transpose<<<dim3(LDIM / 64, HDIM, BDIM), 256, 0, stream>>>(qkv, vT);

  // attention
  attn<<<dim3(LDIM / 64, HDIM, BDIM), 256, 0, stream>>>(qr, kr, vT, ao);

  // output projection: (4096x1024) x (1024x1024)^T
  gemm_bt<<<dim3(ML / 128, DDIM / 128), 256, 0, stream>>>(ao, woutb, out, ML, DDIM, DDIM);
}

// Round 2
// 176.834 us; speedup vs baseline: 1.8336x; 1.8336x over previous
//
#include <hip/hip_runtime.h>
#include <hip/hip_bf16.h>
#include <stdint.h>

// ---------------------------------------------------------------------------
// RoPE self-attention, B=2 L=2048 D=1024 H=16 Dh=64, f32 in/out, bf16 MFMA core
// ---------------------------------------------------------------------------

typedef __attribute__((ext_vector_type(8))) short short8;
typedef __attribute__((ext_vector_type(4))) float floatx4;

#define BDIM 2
#define LDIM 2048
#define DDIM 1024
#define HDIM 16
#define DH 64
#define ML (BDIM * LDIM)   // 4096 rows

// f32 -> bf16 round-to-nearest-even
__device__ __forceinline__ uint16_t f2b(float x) {
  uint32_t b = __float_as_uint(x);
  b += 0x7FFFu + ((b >> 16) & 1u);
  return (uint16_t)(b >> 16);
}

__device__ __forceinline__ uint32_t pack2(float a, float b) {
  return (uint32_t)f2b(a) | ((uint32_t)f2b(b) << 16);
}

__device__ __forceinline__ void load_lds_16B(const uint16_t* g, uint16_t* l) {
  __builtin_amdgcn_global_load_lds(
      (const __attribute__((address_space(1))) void*)g,
      (__attribute__((address_space(3))) void*)l, 16, 0, 0);
}

// ---------------- convert f32 -> bf16, 4 elems/thread ----------------------
__global__ void cvt_bf16_x4(const float* __restrict__ in, uint16_t* __restrict__ out, int n4) {
  int i = blockIdx.x * 256 + threadIdx.x;
  if (i >= n4) return;
  float4 v = ((const float4*)in)[i];
  ((uint2*)out)[i] = make_uint2(pack2(v.x, v.y), pack2(v.z, v.w));
}

// ---------------- rope cos/sin table: [L][32] ------------------------------
__global__ void rope_table(float* __restrict__ cosT, float* __restrict__ sinT) {
  int i = blockIdx.x * 256 + threadIdx.x;  // L*32 = 65536
  int l = i >> 5, f = i & 31;
  float invf = exp2f(-(float)f * (13.287712379549449f / 32.f));
  float ang = (float)l * invf;
  cosT[i] = cosf(ang);
  sinT[i] = sinf(ang);
}

// ---------------- GEMM (bt): C[m][n] = sum_k A[m][k]*B[n][k] ---------------
__global__ __launch_bounds__(256) void gemm_bt(const uint16_t* __restrict__ A,
                                               const uint16_t* __restrict__ B,
                                               float* __restrict__ C,
                                               int M, int N, int K) {
  __shared__ uint16_t As[128 * 32];
  __shared__ uint16_t Bs[128 * 32];
  const int m0 = blockIdx.x * 128;
  const int n0 = blockIdx.y * 128;
  const int t = threadIdx.x;
  const int lane = t & 63;
  const int w = t >> 6;
  const int wr = w >> 1, wc = w & 1;
  const int srow = t >> 2;
  const int scol = (t & 3) * 8;
  const int c0 = lane & 15, c1 = lane >> 4;

  floatx4 acc[4][4];
#pragma unroll
  for (int i = 0; i < 4; ++i)
#pragma unroll
    for (int j = 0; j < 4; ++j) acc[i][j] = (floatx4){0.f, 0.f, 0.f, 0.f};

  for (int k0 = 0; k0 < K; k0 += 32) {
    const uint16_t* ga = A + (size_t)(m0 + srow) * K + k0 + scol;
    load_lds_16B(ga, &As[t * 8]);
    load_lds_16B(ga + (size_t)64 * K, &As[t * 8 + 64 * 32]);
    const uint16_t* gb = B + (size_t)(n0 + srow) * K + k0 + scol;
    load_lds_16B(gb, &Bs[t * 8]);
    load_lds_16B(gb + (size_t)64 * K, &Bs[t * 8 + 64 * 32]);
    __syncthreads();

    short8 a[4], b[4];
#pragma unroll
    for (int i = 0; i < 4; ++i)
      a[i] = *(const short8*)&As[(wr * 64 + i * 16 + c0) * 32 + c1 * 8];
#pragma unroll
    for (int j = 0; j < 4; ++j)
      b[j] = *(const short8*)&Bs[(wc * 64 + j * 16 + c0) * 32 + c1 * 8];
#pragma unroll
    for (int i = 0; i < 4; ++i)
#pragma unroll
      for (int j = 0; j < 4; ++j)
        acc[i][j] = __builtin_amdgcn_mfma_f32_16x16x32_bf16(a[i], b[j], acc[i][j], 0, 0, 0);
    __syncthreads();
  }

#pragma unroll
  for (int i = 0; i < 4; ++i)
#pragma unroll
    for (int j = 0; j < 4; ++j) {
      int row = m0 + wr * 64 + i * 16 + c1 * 4;
      int col = n0 + wc * 64 + j * 16 + c0;
      float* cp = C + (size_t)row * N + col;
#pragma unroll
      for (int r = 0; r < 4; ++r) cp[(size_t)r * N] = acc[i][j][r];
    }
}

// ---------------- RoPE apply: qkv f32 -> qr, kr bf16 (b,h,l,dh) ------------
__global__ void rope_apply(const float* __restrict__ qkv,
                           const float* __restrict__ cosT,
                           const float* __restrict__ sinT,
                           uint16_t* __restrict__ qr, uint16_t* __restrict__ kr) {
  int idx = blockIdx.x * 256 + threadIdx.x;
  int m = idx >> 10;
  int e = idx & 1023;
  int h = e >> 6, dh = e & 63;
  int l = m & (LDIM - 1), b = m >> 11;
  int f = dh & 31;
  float c = cosT[l * 32 + f], s = sinT[l * 32 + f];
  size_t base = (size_t)m * (3 * DDIM);
  float q = qkv[base + e];
  float k = qkv[base + DDIM + e];
  int other = (e & ~63) | ((dh < 32) ? dh + 32 : dh - 32);
  float qo = qkv[base + other];
  float ko = qkv[base + DDIM + other];
  float sgn = (dh < 32) ? -1.f : 1.f;
  float qq = q * c + sgn * qo * s;
  float kk = k * c + sgn * ko * s;
  size_t o = ((size_t)((b * HDIM + h) * LDIM + l)) * DH + dh;
  qr[o] = f2b(qq);
  kr[o] = f2b(kk);
}

// ---------------- V transpose: qkv v-part -> vT bf16 (b,h,dh,L) ------------
__global__ void v_transpose(const float* __restrict__ qkv, uint16_t* __restrict__ vT) {
  __shared__ float tile[64][65];
  int b = blockIdx.z, h = blockIdx.y, l0 = blockIdx.x * 64;
  int tx = threadIdx.x & 63, ty = threadIdx.x >> 6;
#pragma unroll
  for (int rr = 0; rr < 16; ++rr) {
    int row = rr * 4 + ty;
    tile[row][tx] = qkv[((size_t)(b * LDIM + l0 + row)) * (3 * DDIM) + 2 * DDIM + h * DH + tx];
  }
  __syncthreads();
#pragma unroll
  for (int rr = 0; rr < 16; ++rr) {
    int drow = rr * 4 + ty;
    vT[((size_t)((b * HDIM + h) * DH + drow)) * LDIM + l0 + tx] = f2b(tile[tx][drow]);
  }
}

// ---------------- flash attention (rewritten) ------------------------------
// grid (L/64, H, B), 256 threads = 4 waves, each wave owns 16 q-rows.
// K,V tiles (64 kv) staged cooperatively in swizzled LDS, double-buffered.
// Doubly-swapped MFMA: S^T = mfma(K,Q)  -> q is lane-local (col=lane&15)
//                      O^T = mfma(V^T,P)-> q stays lane-local; softmax has
// only 2 shfl_xor per iter; rescale + 1/lsum are lane-local.
// LDS swizzle everywhere: byte ^= ((row&7)<<4) on 128-byte rows.

// element index in a [rows][64] bf16 tile with swizzle
#define SWZ(row, colb) (((row) << 6) + ((((colb) ^ (((row) & 7) << 4))) >> 1))

__global__ __launch_bounds__(256) void attn(const uint16_t* __restrict__ qr,
                                            const uint16_t* __restrict__ kr,
                                            const uint16_t* __restrict__ vT,
                                            uint16_t* __restrict__ out) {
  __shared__ uint16_t Ks[2][64 * 64];
  __shared__ uint16_t Vs[2][64 * 64];
  __shared__ uint16_t Pl[4][16 * 64];
  const int t = threadIdx.x, lane = t & 63, w = t >> 6;
  const int b = blockIdx.z, h = blockIdx.y;
  const int bh = b * HDIM + h;
  const int c0 = lane & 15, c1 = lane >> 4;
  const int l0 = blockIdx.x * 64 + w * 16;
  const uint16_t* Q = qr + (size_t)bh * LDIM * DH;
  const char* Kp = (const char*)(kr + (size_t)bh * LDIM * DH);
  const char* Vp = (const char*)(vT + (size_t)bh * DH * LDIM);

  // staging geometry: thread covers rows (t>>3) and (t>>3)+32, 16B column chunk
  const int srow = t >> 3;
  const int scolb = (t & 7) * 16;
  const int scsw = scolb ^ ((srow & 7) << 4);  // same for srow and srow+32

  // Q fragments (b-operand of QK): lane holds Q[l0+c0][c1*8 + half*32]
  short8 qf0 = *(const short8*)&Q[(size_t)(l0 + c0) * DH + c1 * 8];
  short8 qf1 = *(const short8*)&Q[(size_t)(l0 + c0) * DH + 32 + c1 * 8];

  const int swq = (c0 & 7) << 4;  // swizzle term for rows indexed by c0

  float m = -1e30f, lsum = 0.f;
  floatx4 accO[4];
#pragma unroll
  for (int nt = 0; nt < 4; ++nt) accO[nt] = (floatx4){0.f, 0.f, 0.f, 0.f};

  // prologue: stage tile 0 into buffer 0
  load_lds_16B((const uint16_t*)(Kp + (size_t)srow * 128 + scsw), &Ks[0][t * 8]);
  load_lds_16B((const uint16_t*)(Kp + (size_t)(srow + 32) * 128 + scsw), &Ks[0][2048 + t * 8]);
  load_lds_16B((const uint16_t*)(Vp + (size_t)srow * (LDIM * 2) + scsw), &Vs[0][t * 8]);
  load_lds_16B((const uint16_t*)(Vp + (size_t)(srow + 32) * (LDIM * 2) + scsw), &Vs[0][2048 + t * 8]);
  __syncthreads();

  int cur = 0;
  for (int it = 0; it < LDIM / 64; ++it) {
    // stage next tile into the other buffer (overlaps with compute below)
    if (it < LDIM / 64 - 1) {
      int kv0 = (it + 1) * 64;
      load_lds_16B((const uint16_t*)(Kp + (size_t)(kv0 + srow) * 128 + scsw), &Ks[cur ^ 1][t * 8]);
      load_lds_16B((const uint16_t*)(Kp + (size_t)(kv0 + srow + 32) * 128 + scsw), &Ks[cur ^ 1][2048 + t * 8]);
      load_lds_16B((const uint16_t*)(Vp + (size_t)srow * (LDIM * 2) + kv0 * 2 + scsw), &Vs[cur ^ 1][t * 8]);
      load_lds_16B((const uint16_t*)(Vp + (size_t)(srow + 32) * (LDIM * 2) + kv0 * 2 + scsw), &Vs[cur ^ 1][2048 + t * 8]);
    }

    const uint16_t* kt = &Ks[cur][0];
    const uint16_t* vt = &Vs[cur][0];

    // ---- S^T = K · Q^T : lane holds S[q=c0][kv = nt*16 + c1*4 + r] ----
    floatx4 s[4];
#pragma unroll
    for (int nt = 0; nt < 4; ++nt) {
      short8 ka0 = *(const short8*)&kt[SWZ(nt * 16 + c0, c1 * 16)];
      short8 ka1 = *(const short8*)&kt[SWZ(nt * 16 + c0, 64 + c1 * 16)];
      floatx4 z = (floatx4){0.f, 0.f, 0.f, 0.f};
      z = __builtin_amdgcn_mfma_f32_16x16x32_bf16(ka0, qf0, z, 0, 0, 0);
      z = __builtin_amdgcn_mfma_f32_16x16x32_bf16(ka1, qf1, z, 0, 0, 0);
      s[nt] = z * 0.125f;
    }

    // ---- online softmax: q-row is lane-local (c0); combine 4 c1-groups ----
    float tmax = s[0][0];
#pragma unroll
    for (int nt = 0; nt < 4; ++nt)
#pragma unroll
      for (int r = 0; r < 4; ++r) tmax = fmaxf(tmax, s[nt][r]);
    tmax = fmaxf(tmax, __shfl_xor(tmax, 16));
    tmax = fmaxf(tmax, __shfl_xor(tmax, 32));
    float mn = fmaxf(m, tmax);
    float scl = __expf(m - mn);
    m = mn;
    float ts = 0.f;
#pragma unroll
    for (int nt = 0; nt < 4; ++nt) {
      float e0 = __expf(s[nt][0] - mn);
      float e1 = __expf(s[nt][1] - mn);
      float e2 = __expf(s[nt][2] - mn);
      float e3 = __expf(s[nt][3] - mn);
      ts += (e0 + e1) + (e2 + e3);
      uint2 pw = make_uint2(pack2(e0, e1), pack2(e2, e3));
      // P[q=c0][kv = nt*16 + c1*4 .. +3], swizzled
      *(uint2*)&Pl[w][(c0 << 6) + ((((nt * 32 + c1 * 8)) ^ swq) >> 1)] = pw;
    }
    ts += __shfl_xor(ts, 16);
    ts += __shfl_xor(ts, 32);
    lsum = lsum * scl + ts;
#pragma unroll
    for (int nt = 0; nt < 4; ++nt) accO[nt] *= scl;

    // ---- O^T += V^T · P^T : lane keeps q=c0, dh = nt*16 + c1*4 + r ----
    short8 pb0 = *(const short8*)&Pl[w][(c0 << 6) + (((c1 * 16) ^ swq) >> 1)];
    short8 pb1 = *(const short8*)&Pl[w][(c0 << 6) + (((64 + c1 * 16) ^ swq) >> 1)];
#pragma unroll
    for (int nt = 0; nt < 4; ++nt) {
      short8 va0 = *(const short8*)&vt[SWZ(nt * 16 + c0, c1 * 16)];
      short8 va1 = *(const short8*)&vt[SWZ(nt * 16 + c0, 64 + c1 * 16)];
      accO[nt] = __builtin_amdgcn_mfma_f32_16x16x32_bf16(va0, pb0, accO[nt], 0, 0, 0);
      accO[nt] = __builtin_amdgcn_mfma_f32_16x16x32_bf16(va1, pb1, accO[nt], 0, 0, 0);
    }

    __syncthreads();  // drains staging loads (vmcnt 0) + protects buffer swap
    cur ^= 1;
  }

  // ---- finalize: q = c0 lane-local; dh = nt*16 + c1*4 + r ----
  float inv = 1.f / lsum;
  size_t orow = (size_t)(b * LDIM + blockIdx.x * 64 + w * 16 + c0);
  uint16_t* op = out + orow * DDIM + h * DH;
#pragma unroll
  for (int nt = 0; nt < 4; ++nt) {
    uint2 ov = make_uint2(pack2(accO[nt][0] * inv, accO[nt][1] * inv),
                          pack2(accO[nt][2] * inv, accO[nt][3] * inv));
    *(uint2*)&op[nt * 16 + c1 * 4] = ov;
  }
}

// ---------------- workspace layout -----------------------------------------
static constexpr size_t OFF_XB    = 0;
static constexpr size_t OFF_WQKVB = (size_t)8 << 20;
static constexpr size_t OFF_WOUTB = (size_t)14 << 20;
static constexpr size_t OFF_QKV   = (size_t)16 << 20;
static constexpr size_t OFF_QR    = (size_t)64 << 20;
static constexpr size_t OFF_KR    = (size_t)72 << 20;
static constexpr size_t OFF_VT    = (size_t)80 << 20;
static constexpr size_t OFF_AO    = (size_t)88 << 20;
static constexpr size_t OFF_COS   = (size_t)96 << 20;
static constexpr size_t OFF_SIN   = OFF_COS + ((size_t)256 << 10);

extern "C" void kernel_launch(void* const* d_in, const int* in_sizes, int n_in,
                              void* d_out, int out_size, void* d_ws, size_t ws_size,
                              hipStream_t stream) {
  const float* x     = (const float*)d_in[0];
  const float* w_qkv = (const float*)d_in[1];
  const float* w_out = (const float*)d_in[2];
  float* out = (float*)d_out;
  char* ws = (char*)d_ws;

  uint16_t* xb    = (uint16_t*)(ws + OFF_XB);
  uint16_t* wqkvb = (uint16_t*)(ws + OFF_WQKVB);
  uint16_t* woutb = (uint16_t*)(ws + OFF_WOUTB);
  float*    qkv   = (float*)(ws + OFF_QKV);
  uint16_t* qr    = (uint16_t*)(ws + OFF_QR);
  uint16_t* kr    = (uint16_t*)(ws + OFF_KR);
  uint16_t* vT    = (uint16_t*)(ws + OFF_VT);
  uint16_t* ao    = (uint16_t*)(ws + OFF_AO);
  float*    cosT  = (float*)(ws + OFF_COS);
  float*    sinT  = (float*)(ws + OFF_SIN);

  cvt_bf16_x4<<<(ML * DDIM / 4 + 255) / 256, 256, 0, stream>>>(x, xb, ML * DDIM / 4);
  cvt_bf16_x4<<<(3 * DDIM * DDIM / 4 + 255) / 256, 256, 0, stream>>>(w_qkv, wqkvb, 3 * DDIM * DDIM / 4);
  cvt_bf16_x4<<<(DDIM * DDIM / 4 + 255) / 256, 256, 0, stream>>>(w_out, woutb, DDIM * DDIM / 4);
  rope_table<<<(LDIM * 32) / 256, 256, 0, stream>>>(cosT, sinT);

  gemm_bt<<<dim3(ML / 128, 3 * DDIM / 128), 256, 0, stream>>>(xb, wqkvb, qkv, ML, 3 * DDIM, DDIM);

  rope_apply<<<(ML * DDIM) / 256, 256, 0, stream>>>(qkv, cosT, sinT, qr, kr);
  v_transpose<<<dim3(LDIM / 64, HDIM, BDIM), 256, 0, stream>>>(qkv, vT);

  attn<<<dim3(LDIM / 64, HDIM, BDIM), 256, 0, stream>>>(qr, kr, vT, ao);

  gemm_bt<<<dim3(ML / 128, DDIM / 128), 256, 0, stream>>>(ao, woutb, out, ML, DDIM, DDIM);
}

// Round 3
// 165.263 us; speedup vs baseline: 1.9619x; 1.0700x over previous
//
#include <hip/hip_runtime.h>
#include <hip/hip_bf16.h>
#include <stdint.h>

// ---------------------------------------------------------------------------
// RoPE self-attention, B=2 L=2048 D=1024 H=16 Dh=64, f32 in/out, bf16 MFMA core
// ---------------------------------------------------------------------------

typedef __attribute__((ext_vector_type(8))) short short8;
typedef __attribute__((ext_vector_type(4))) float floatx4;

#define BDIM 2
#define LDIM 2048
#define DDIM 1024
#define HDIM 16
#define DH 64
#define ML (BDIM * LDIM)   // 4096 rows

// log2(e) * (1/sqrt(Dh)) folded into Q at the producer -> attn softmax runs
// in exp2 domain with no per-element scaling.
#define QSCALE 0.18033688011112042f

// f32 -> bf16 round-to-nearest-even
__device__ __forceinline__ uint16_t f2b(float x) {
  uint32_t b = __float_as_uint(x);
  b += 0x7FFFu + ((b >> 16) & 1u);
  return (uint16_t)(b >> 16);
}

__device__ __forceinline__ uint32_t pack2(float a, float b) {
  return (uint32_t)f2b(a) | ((uint32_t)f2b(b) << 16);
}

// packed f32x2 -> bf16x2 in one instruction (RNE)
__device__ __forceinline__ uint32_t cvtpk(float lo, float hi) {
  uint32_t r;
  asm("v_cvt_pk_bf16_f32 %0, %1, %2" : "=v"(r) : "v"(lo), "v"(hi));
  return r;
}

__device__ __forceinline__ void load_lds_16B(const uint16_t* g, uint16_t* l) {
  __builtin_amdgcn_global_load_lds(
      (const __attribute__((address_space(1))) void*)g,
      (__attribute__((address_space(3))) void*)l, 16, 0, 0);
}

// ---------------- convert f32 -> bf16, 4 elems/thread ----------------------
__global__ void cvt_bf16_x4(const float* __restrict__ in, uint16_t* __restrict__ out, int n4) {
  int i = blockIdx.x * 256 + threadIdx.x;
  if (i >= n4) return;
  float4 v = ((const float4*)in)[i];
  ((uint2*)out)[i] = make_uint2(pack2(v.x, v.y), pack2(v.z, v.w));
}

// ---------------- rope cos/sin table: [L][32] ------------------------------
__global__ void rope_table(float* __restrict__ cosT, float* __restrict__ sinT) {
  int i = blockIdx.x * 256 + threadIdx.x;  // L*32 = 65536
  int l = i >> 5, f = i & 31;
  float invf = exp2f(-(float)f * (13.287712379549449f / 32.f));
  float ang = (float)l * invf;
  cosT[i] = cosf(ang);
  sinT[i] = sinf(ang);
}

// ---------------- plain GEMM (bt) for the output projection ----------------
__global__ __launch_bounds__(256) void gemm_bt(const uint16_t* __restrict__ A,
                                               const uint16_t* __restrict__ B,
                                               float* __restrict__ C,
                                               int M, int N, int K) {
  __shared__ uint16_t As[128 * 32];
  __shared__ uint16_t Bs[128 * 32];
  const int m0 = blockIdx.x * 128;
  const int n0 = blockIdx.y * 128;
  const int t = threadIdx.x;
  const int lane = t & 63;
  const int w = t >> 6;
  const int wr = w >> 1, wc = w & 1;
  const int srow = t >> 2;
  const int scol = (t & 3) * 8;
  const int c0 = lane & 15, c1 = lane >> 4;

  floatx4 acc[4][4];
#pragma unroll
  for (int i = 0; i < 4; ++i)
#pragma unroll
    for (int j = 0; j < 4; ++j) acc[i][j] = (floatx4){0.f, 0.f, 0.f, 0.f};

  for (int k0 = 0; k0 < K; k0 += 32) {
    const uint16_t* ga = A + (size_t)(m0 + srow) * K + k0 + scol;
    load_lds_16B(ga, &As[t * 8]);
    load_lds_16B(ga + (size_t)64 * K, &As[t * 8 + 64 * 32]);
    const uint16_t* gb = B + (size_t)(n0 + srow) * K + k0 + scol;
    load_lds_16B(gb, &Bs[t * 8]);
    load_lds_16B(gb + (size_t)64 * K, &Bs[t * 8 + 64 * 32]);
    __syncthreads();

    short8 a[4], b[4];
#pragma unroll
    for (int i = 0; i < 4; ++i)
      a[i] = *(const short8*)&As[(wr * 64 + i * 16 + c0) * 32 + c1 * 8];
#pragma unroll
    for (int j = 0; j < 4; ++j)
      b[j] = *(const short8*)&Bs[(wc * 64 + j * 16 + c0) * 32 + c1 * 8];
#pragma unroll
    for (int i = 0; i < 4; ++i)
#pragma unroll
      for (int j = 0; j < 4; ++j)
        acc[i][j] = __builtin_amdgcn_mfma_f32_16x16x32_bf16(a[i], b[j], acc[i][j], 0, 0, 0);
    __syncthreads();
  }

#pragma unroll
  for (int i = 0; i < 4; ++i)
#pragma unroll
    for (int j = 0; j < 4; ++j) {
      int row = m0 + wr * 64 + i * 16 + c1 * 4;
      int col = n0 + wc * 64 + j * 16 + c0;
      float* cp = C + (size_t)row * N + col;
#pragma unroll
      for (int r = 0; r < 4; ++r) cp[(size_t)r * N] = acc[i][j][r];
    }
}

// ---------------- fused QKV GEMM: epilogue applies RoPE + layout -----------
// A: xb (ML x 1024), B: wqkvb (3072 x 1024). Instead of writing C f32, the
// epilogue writes:  q -> qr (b,h,l,dh) bf16, rope'd and *QSCALE
//                   k -> kr (b,h,l,dh) bf16, rope'd
//                   v -> vT (b,h,dh,l) bf16 (transposed store)
// Rotation partner col^32 lives in acc[i][j^2] (heads are 64-aligned).
__global__ __launch_bounds__(256) void gemm_qkv_rope(const uint16_t* __restrict__ A,
                                                     const uint16_t* __restrict__ B,
                                                     const float* __restrict__ cosT,
                                                     const float* __restrict__ sinT,
                                                     uint16_t* __restrict__ qr,
                                                     uint16_t* __restrict__ kr,
                                                     uint16_t* __restrict__ vT) {
  constexpr int K = DDIM;
  __shared__ uint16_t As[128 * 32];
  __shared__ uint16_t Bs[128 * 32];
  const int m0 = blockIdx.x * 128;
  const int n0 = blockIdx.y * 128;
  const int t = threadIdx.x;
  const int lane = t & 63;
  const int w = t >> 6;
  const int wr = w >> 1, wc = w & 1;
  const int srow = t >> 2;
  const int scol = (t & 3) * 8;
  const int c0 = lane & 15, c1 = lane >> 4;

  floatx4 acc[4][4];
#pragma unroll
  for (int i = 0; i < 4; ++i)
#pragma unroll
    for (int j = 0; j < 4; ++j) acc[i][j] = (floatx4){0.f, 0.f, 0.f, 0.f};

  for (int k0 = 0; k0 < K; k0 += 32) {
    const uint16_t* ga = A + (size_t)(m0 + srow) * K + k0 + scol;
    load_lds_16B(ga, &As[t * 8]);
    load_lds_16B(ga + (size_t)64 * K, &As[t * 8 + 64 * 32]);
    const uint16_t* gb = B + (size_t)(n0 + srow) * K + k0 + scol;
    load_lds_16B(gb, &Bs[t * 8]);
    load_lds_16B(gb + (size_t)64 * K, &Bs[t * 8 + 64 * 32]);
    __syncthreads();

    short8 a[4], b[4];
#pragma unroll
    for (int i = 0; i < 4; ++i)
      a[i] = *(const short8*)&As[(wr * 64 + i * 16 + c0) * 32 + c1 * 8];
#pragma unroll
    for (int j = 0; j < 4; ++j)
      b[j] = *(const short8*)&Bs[(wc * 64 + j * 16 + c0) * 32 + c1 * 8];
#pragma unroll
    for (int i = 0; i < 4; ++i)
#pragma unroll
      for (int j = 0; j < 4; ++j)
        acc[i][j] = __builtin_amdgcn_mfma_f32_16x16x32_bf16(a[i], b[j], acc[i][j], 0, 0, 0);
    __syncthreads();
  }

  // ---- epilogue ----
#pragma unroll
  for (int j = 0; j < 4; ++j) {
    const int col = n0 + wc * 64 + j * 16 + c0;   // 0..3071, wave-uniform section
    const int sec = col >> 10;                    // 0=q 1=k 2=v
    const int e = col & 1023;
    const int h = e >> 6, dh = e & 63;
#pragma unroll
    for (int i = 0; i < 4; ++i) {
      const int row = m0 + wr * 64 + i * 16 + c1 * 4;  // b*L + l, multiple of 4
      const int bb = row >> 11;
      const int l = row & 2047;
      if (sec == 2) {
        uint16_t* vp = vT + ((size_t)((bb * HDIM + h) * DH + dh)) * LDIM + l;
#pragma unroll
        for (int r = 0; r < 4; ++r) vp[r] = f2b(acc[i][j][r]);
      } else {
        const float sgn = (dh < 32) ? -1.f : 1.f;
        const float sc = (sec == 0) ? QSCALE : 1.f;
        uint16_t* dp = (sec == 0 ? qr : kr) + ((size_t)((bb * HDIM + h) * LDIM + l)) * DH + dh;
        const int fi = l * 32 + (dh & 31);
#pragma unroll
        for (int r = 0; r < 4; ++r) {
          float cv = cosT[fi + r * 32];
          float sv = sinT[fi + r * 32];
          float o = (acc[i][j][r] * cv + sgn * acc[i][j ^ 2][r] * sv) * sc;
          dp[(size_t)r * DH] = f2b(o);
        }
      }
    }
  }
}

// ---------------- flash attention ------------------------------------------
// grid (L/128, H, B), 256 threads = 4 waves, each wave owns 32 q-rows
// (2 Q-subtiles of 16). K frags held in regs across both subtiles; V frags
// held across sub1. Softmax in exp2 domain (scale pre-folded into Q),
// defer-max (THR=8), cvt_pk packing. One barrier per KV tile.

#define SWZ(row, colb) (((row) << 6) + ((((colb) ^ (((row) & 7) << 4))) >> 1))

__device__ __forceinline__ void softmax_pack(floatx4 s[4], float& m, float& lsum,
                                             floatx4 accO[4], uint16_t* pl,
                                             int c0, int c1, int swq) {
  float t0 = fmaxf(fmaxf(s[0][0], s[0][1]), fmaxf(s[0][2], s[0][3]));
  float t1 = fmaxf(fmaxf(s[1][0], s[1][1]), fmaxf(s[1][2], s[1][3]));
  float t2 = fmaxf(fmaxf(s[2][0], s[2][1]), fmaxf(s[2][2], s[2][3]));
  float t3 = fmaxf(fmaxf(s[3][0], s[3][1]), fmaxf(s[3][2], s[3][3]));
  float tmax = fmaxf(fmaxf(t0, t1), fmaxf(t2, t3));
  tmax = fmaxf(tmax, __shfl_xor(tmax, 16));
  tmax = fmaxf(tmax, __shfl_xor(tmax, 32));
  if (!__all(tmax <= m + 8.f)) {       // defer-max: rescale only on real growth
    float mn = fmaxf(m, tmax);
    float scl = __builtin_amdgcn_exp2f(m - mn);
    lsum *= scl;
#pragma unroll
    for (int nt = 0; nt < 4; ++nt) accO[nt] *= scl;
    m = mn;
  }
  float ts = 0.f;
#pragma unroll
  for (int nt = 0; nt < 4; ++nt) {
    float e0 = __builtin_amdgcn_exp2f(s[nt][0] - m);
    float e1 = __builtin_amdgcn_exp2f(s[nt][1] - m);
    float e2 = __builtin_amdgcn_exp2f(s[nt][2] - m);
    float e3 = __builtin_amdgcn_exp2f(s[nt][3] - m);
    ts += (e0 + e1) + (e2 + e3);
    *(uint2*)&pl[(c0 << 6) + ((((nt * 32 + c1 * 8)) ^ swq) >> 1)] =
        make_uint2(cvtpk(e0, e1), cvtpk(e2, e3));
  }
  ts += __shfl_xor(ts, 16);
  ts += __shfl_xor(ts, 32);
  lsum += ts;
}

__global__ __launch_bounds__(256) void attn(const uint16_t* __restrict__ qr,
                                            const uint16_t* __restrict__ kr,
                                            const uint16_t* __restrict__ vT,
                                            uint16_t* __restrict__ out) {
  __shared__ uint16_t Ks[2][64 * 64];
  __shared__ uint16_t Vs[2][64 * 64];
  __shared__ uint16_t Pl[4][16 * 64];
  const int t = threadIdx.x, lane = t & 63, w = t >> 6;
  const int b = blockIdx.z, h = blockIdx.y;
  const int bh = b * HDIM + h;
  const int c0 = lane & 15, c1 = lane >> 4;
  const uint16_t* Qb = qr + (size_t)bh * LDIM * DH;
  const char* Kp = (const char*)(kr + (size_t)bh * LDIM * DH);
  const char* Vp = (const char*)(vT + (size_t)bh * DH * LDIM);
  uint16_t* pl = &Pl[w][0];

  const int srow = t >> 3;
  const int scolb = (t & 7) * 16;
  const int scsw = scolb ^ ((srow & 7) << 4);

  const int qrow = blockIdx.x * 128 + w * 32 + c0;
  short8 qf00 = *(const short8*)&Qb[(size_t)qrow * DH + c1 * 8];
  short8 qf01 = *(const short8*)&Qb[(size_t)qrow * DH + 32 + c1 * 8];
  short8 qf10 = *(const short8*)&Qb[(size_t)(qrow + 16) * DH + c1 * 8];
  short8 qf11 = *(const short8*)&Qb[(size_t)(qrow + 16) * DH + 32 + c1 * 8];

  const int swq = (c0 & 7) << 4;

  float m0_ = -1e30f, lsum0_ = 0.f, m1_ = -1e30f, lsum1_ = 0.f;
  floatx4 accO0[4], accO1[4];
#pragma unroll
  for (int nt = 0; nt < 4; ++nt) {
    accO0[nt] = (floatx4){0.f, 0.f, 0.f, 0.f};
    accO1[nt] = (floatx4){0.f, 0.f, 0.f, 0.f};
  }

  // prologue: stage tile 0 into buffer 0
  load_lds_16B((const uint16_t*)(Kp + (size_t)srow * 128 + scsw), &Ks[0][t * 8]);
  load_lds_16B((const uint16_t*)(Kp + (size_t)(srow + 32) * 128 + scsw), &Ks[0][2048 + t * 8]);
  load_lds_16B((const uint16_t*)(Vp + (size_t)srow * (LDIM * 2) + scsw), &Vs[0][t * 8]);
  load_lds_16B((const uint16_t*)(Vp + (size_t)(srow + 32) * (LDIM * 2) + scsw), &Vs[0][2048 + t * 8]);
  __syncthreads();

  int cur = 0;
  for (int it = 0; it < LDIM / 64; ++it) {
    if (it < LDIM / 64 - 1) {
      int kv0 = (it + 1) * 64;
      load_lds_16B((const uint16_t*)(Kp + (size_t)(kv0 + srow) * 128 + scsw), &Ks[cur ^ 1][t * 8]);
      load_lds_16B((const uint16_t*)(Kp + (size_t)(kv0 + srow + 32) * 128 + scsw), &Ks[cur ^ 1][2048 + t * 8]);
      load_lds_16B((const uint16_t*)(Vp + (size_t)srow * (LDIM * 2) + kv0 * 2 + scsw), &Vs[cur ^ 1][t * 8]);
      load_lds_16B((const uint16_t*)(Vp + (size_t)(srow + 32) * (LDIM * 2) + kv0 * 2 + scsw), &Vs[cur ^ 1][2048 + t * 8]);
    }

    const uint16_t* kt = &Ks[cur][0];
    const uint16_t* vt = &Vs[cur][0];

    // K fragments, held for both subtiles
    short8 ka0[4], ka1[4];
#pragma unroll
    for (int nt = 0; nt < 4; ++nt) {
      ka0[nt] = *(const short8*)&kt[SWZ(nt * 16 + c0, c1 * 16)];
      ka1[nt] = *(const short8*)&kt[SWZ(nt * 16 + c0, 64 + c1 * 16)];
    }

    // ---- subtile 0: QK ----
    floatx4 s[4];
    __builtin_amdgcn_s_setprio(1);
#pragma unroll
    for (int nt = 0; nt < 4; ++nt) {
      floatx4 z = (floatx4){0.f, 0.f, 0.f, 0.f};
      z = __builtin_amdgcn_mfma_f32_16x16x32_bf16(ka0[nt], qf00, z, 0, 0, 0);
      z = __builtin_amdgcn_mfma_f32_16x16x32_bf16(ka1[nt], qf01, z, 0, 0, 0);
      s[nt] = z;
    }
    __builtin_amdgcn_s_setprio(0);
    softmax_pack(s, m0_, lsum0_, accO0, pl, c0, c1, swq);
    short8 pb0 = *(const short8*)&pl[(c0 << 6) + (((c1 * 16) ^ swq) >> 1)];
    short8 pb1 = *(const short8*)&pl[(c0 << 6) + (((64 + c1 * 16) ^ swq) >> 1)];
    // V fragments, held through subtile 1
    short8 va0[4], va1[4];
#pragma unroll
    for (int nt = 0; nt < 4; ++nt) {
      va0[nt] = *(const short8*)&vt[SWZ(nt * 16 + c0, c1 * 16)];
      va1[nt] = *(const short8*)&vt[SWZ(nt * 16 + c0, 64 + c1 * 16)];
    }
    __builtin_amdgcn_s_setprio(1);
#pragma unroll
    for (int nt = 0; nt < 4; ++nt) {
      accO0[nt] = __builtin_amdgcn_mfma_f32_16x16x32_bf16(va0[nt], pb0, accO0[nt], 0, 0, 0);
      accO0[nt] = __builtin_amdgcn_mfma_f32_16x16x32_bf16(va1[nt], pb1, accO0[nt], 0, 0, 0);
    }
    __builtin_amdgcn_s_setprio(0);

    // ---- subtile 1: QK (K frags reused) ----
    __builtin_amdgcn_s_setprio(1);
#pragma unroll
    for (int nt = 0; nt < 4; ++nt) {
      floatx4 z = (floatx4){0.f, 0.f, 0.f, 0.f};
      z = __builtin_amdgcn_mfma_f32_16x16x32_bf16(ka0[nt], qf10, z, 0, 0, 0);
      z = __builtin_amdgcn_mfma_f32_16x16x32_bf16(ka1[nt], qf11, z, 0, 0, 0);
      s[nt] = z;
    }
    __builtin_amdgcn_s_setprio(0);
    softmax_pack(s, m1_, lsum1_, accO1, pl, c0, c1, swq);
    pb0 = *(const short8*)&pl[(c0 << 6) + (((c1 * 16) ^ swq) >> 1)];
    pb1 = *(const short8*)&pl[(c0 << 6) + (((64 + c1 * 16) ^ swq) >> 1)];
    __builtin_amdgcn_s_setprio(1);
#pragma unroll
    for (int nt = 0; nt < 4; ++nt) {
      accO1[nt] = __builtin_amdgcn_mfma_f32_16x16x32_bf16(va0[nt], pb0, accO1[nt], 0, 0, 0);
      accO1[nt] = __builtin_amdgcn_mfma_f32_16x16x32_bf16(va1[nt], pb1, accO1[nt], 0, 0, 0);
    }
    __builtin_amdgcn_s_setprio(0);

    __syncthreads();
    cur ^= 1;
  }

  // ---- finalize ----
  float inv0 = 1.f / lsum0_;
  float inv1 = 1.f / lsum1_;
  size_t row0 = (size_t)(b * LDIM + blockIdx.x * 128 + w * 32 + c0);
  uint16_t* op0 = out + row0 * DDIM + h * DH;
  uint16_t* op1 = out + (row0 + 16) * DDIM + h * DH;
#pragma unroll
  for (int nt = 0; nt < 4; ++nt) {
    *(uint2*)&op0[nt * 16 + c1 * 4] =
        make_uint2(cvtpk(accO0[nt][0] * inv0, accO0[nt][1] * inv0),
                   cvtpk(accO0[nt][2] * inv0, accO0[nt][3] * inv0));
    *(uint2*)&op1[nt * 16 + c1 * 4] =
        make_uint2(cvtpk(accO1[nt][0] * inv1, accO1[nt][1] * inv1),
                   cvtpk(accO1[nt][2] * inv1, accO1[nt][3] * inv1));
  }
}

// ---------------- workspace layout -----------------------------------------
static constexpr size_t OFF_XB    = 0;                   // 8 MB bf16 x
static constexpr size_t OFF_WQKVB = (size_t)8 << 20;     // 6 MB
static constexpr size_t OFF_WOUTB = (size_t)14 << 20;    // 2 MB
static constexpr size_t OFF_QR    = (size_t)16 << 20;    // 8 MB
static constexpr size_t OFF_KR    = (size_t)24 << 20;    // 8 MB
static constexpr size_t OFF_VT    = (size_t)32 << 20;    // 8 MB
static constexpr size_t OFF_AO    = (size_t)40 << 20;    // 8 MB
static constexpr size_t OFF_COS   = (size_t)48 << 20;    // 256 KB
static constexpr size_t OFF_SIN   = OFF_COS + ((size_t)256 << 10);

extern "C" void kernel_launch(void* const* d_in, const int* in_sizes, int n_in,
                              void* d_out, int out_size, void* d_ws, size_t ws_size,
                              hipStream_t stream) {
  const float* x     = (const float*)d_in[0];
  const float* w_qkv = (const float*)d_in[1];
  const float* w_out = (const float*)d_in[2];
  float* out = (float*)d_out;
  char* ws = (char*)d_ws;

  uint16_t* xb    = (uint16_t*)(ws + OFF_XB);
  uint16_t* wqkvb = (uint16_t*)(ws + OFF_WQKVB);
  uint16_t* woutb = (uint16_t*)(ws + OFF_WOUTB);
  uint16_t* qr    = (uint16_t*)(ws + OFF_QR);
  uint16_t* kr    = (uint16_t*)(ws + OFF_KR);
  uint16_t* vT    = (uint16_t*)(ws + OFF_VT);
  uint16_t* ao    = (uint16_t*)(ws + OFF_AO);
  float*    cosT  = (float*)(ws + OFF_COS);
  float*    sinT  = (float*)(ws + OFF_SIN);

  cvt_bf16_x4<<<(ML * DDIM / 4 + 255) / 256, 256, 0, stream>>>(x, xb, ML * DDIM / 4);
  cvt_bf16_x4<<<(3 * DDIM * DDIM / 4 + 255) / 256, 256, 0, stream>>>(w_qkv, wqkvb, 3 * DDIM * DDIM / 4);
  cvt_bf16_x4<<<(DDIM * DDIM / 4 + 255) / 256, 256, 0, stream>>>(w_out, woutb, DDIM * DDIM / 4);
  rope_table<<<(LDIM * 32) / 256, 256, 0, stream>>>(cosT, sinT);

  // fused QKV projection + RoPE + V-transpose
  gemm_qkv_rope<<<dim3(ML / 128, 3 * DDIM / 128), 256, 0, stream>>>(xb, wqkvb, cosT, sinT, qr, kr, vT);

  // attention
  attn<<<dim3(LDIM / 128, HDIM, BDIM), 256, 0, stream>>>(qr, kr, vT, ao);

  // output projection
  gemm_bt<<<dim3(ML / 128, DDIM / 128), 256, 0, stream>>>(ao, woutb, out, ML, DDIM, DDIM);
}

// Round 6
// 147.734 us; speedup vs baseline: 2.1947x; 1.1187x over previous
//
#include <hip/hip_runtime.h>
#include <hip/hip_bf16.h>
#include <stdint.h>

// ---------------------------------------------------------------------------
// RoPE self-attention, B=2 L=2048 D=1024 H=16 Dh=64, f32 in/out, bf16 MFMA core
// ---------------------------------------------------------------------------

typedef __attribute__((ext_vector_type(8))) short short8;
typedef __attribute__((ext_vector_type(4))) float floatx4;
typedef __attribute__((ext_vector_type(16))) float floatx16;

#define BDIM 2
#define LDIM 2048
#define DDIM 1024
#define HDIM 16
#define DH 64
#define ML (BDIM * LDIM)   // 4096 rows

// log2(e) * (1/sqrt(Dh)) folded into Q at the producer -> attn softmax runs
// in exp2 domain with no per-element scaling.
#define QSCALE 0.18033688011112042f

// f32 -> bf16 round-to-nearest-even
__device__ __forceinline__ uint16_t f2b(float x) {
  uint32_t b = __float_as_uint(x);
  b += 0x7FFFu + ((b >> 16) & 1u);
  return (uint16_t)(b >> 16);
}

__device__ __forceinline__ uint32_t pack2(float a, float b) {
  return (uint32_t)f2b(a) | ((uint32_t)f2b(b) << 16);
}

// packed f32x2 -> bf16x2 in one instruction (RNE)
__device__ __forceinline__ uint32_t cvtpk(float lo, float hi) {
  uint32_t r;
  asm("v_cvt_pk_bf16_f32 %0, %1, %2" : "=v"(r) : "v"(lo), "v"(hi));
  return r;
}

__device__ __forceinline__ float max3f(float a, float b, float c) {
  return fmaxf(fmaxf(a, b), c);
}

__device__ __forceinline__ void load_lds_16B(const uint16_t* g, uint16_t* l) {
  __builtin_amdgcn_global_load_lds(
      (const __attribute__((address_space(1))) void*)g,
      (__attribute__((address_space(3))) void*)l, 16, 0, 0);
}

// ---------------- convert f32 -> bf16, 4 elems/thread ----------------------
__global__ void cvt_bf16_x4(const float* __restrict__ in, uint16_t* __restrict__ out, int n4) {
  int i = blockIdx.x * 256 + threadIdx.x;
  if (i >= n4) return;
  float4 v = ((const float4*)in)[i];
  ((uint2*)out)[i] = make_uint2(pack2(v.x, v.y), pack2(v.z, v.w));
}

// ---------------- rope cos/sin table: [L][32] ------------------------------
__global__ void rope_table(float* __restrict__ cosT, float* __restrict__ sinT) {
  int i = blockIdx.x * 256 + threadIdx.x;  // L*32 = 65536
  int l = i >> 5, f = i & 31;
  float invf = exp2f(-(float)f * (13.287712379549449f / 32.f));
  float ang = (float)l * invf;
  cosT[i] = cosf(ang);
  sinT[i] = sinf(ang);
}

// ---------------- plain GEMM (bt) for the output projection ----------------
__global__ __launch_bounds__(256) void gemm_bt(const uint16_t* __restrict__ A,
                                               const uint16_t* __restrict__ B,
                                               float* __restrict__ C,
                                               int M, int N, int K) {
  __shared__ uint16_t As[128 * 32];
  __shared__ uint16_t Bs[128 * 32];
  const int m0 = blockIdx.x * 128;
  const int n0 = blockIdx.y * 128;
  const int t = threadIdx.x;
  const int lane = t & 63;
  const int w = t >> 6;
  const int wr = w >> 1, wc = w & 1;
  const int srow = t >> 2;
  const int scol = (t & 3) * 8;
  const int c0 = lane & 15, c1 = lane >> 4;

  floatx4 acc[4][4];
#pragma unroll
  for (int i = 0; i < 4; ++i)
#pragma unroll
    for (int j = 0; j < 4; ++j) acc[i][j] = (floatx4){0.f, 0.f, 0.f, 0.f};

  for (int k0 = 0; k0 < K; k0 += 32) {
    const uint16_t* ga = A + (size_t)(m0 + srow) * K + k0 + scol;
    load_lds_16B(ga, &As[t * 8]);
    load_lds_16B(ga + (size_t)64 * K, &As[t * 8 + 64 * 32]);
    const uint16_t* gb = B + (size_t)(n0 + srow) * K + k0 + scol;
    load_lds_16B(gb, &Bs[t * 8]);
    load_lds_16B(gb + (size_t)64 * K, &Bs[t * 8 + 64 * 32]);
    __syncthreads();

    short8 a[4], b[4];
#pragma unroll
    for (int i = 0; i < 4; ++i)
      a[i] = *(const short8*)&As[(wr * 64 + i * 16 + c0) * 32 + c1 * 8];
#pragma unroll
    for (int j = 0; j < 4; ++j)
      b[j] = *(const short8*)&Bs[(wc * 64 + j * 16 + c0) * 32 + c1 * 8];
#pragma unroll
    for (int i = 0; i < 4; ++i)
#pragma unroll
      for (int j = 0; j < 4; ++j)
        acc[i][j] = __builtin_amdgcn_mfma_f32_16x16x32_bf16(a[i], b[j], acc[i][j], 0, 0, 0);
    __syncthreads();
  }

#pragma unroll
  for (int i = 0; i < 4; ++i)
#pragma unroll
    for (int j = 0; j < 4; ++j) {
      int row = m0 + wr * 64 + i * 16 + c1 * 4;
      int col = n0 + wc * 64 + j * 16 + c0;
      float* cp = C + (size_t)row * N + col;
#pragma unroll
      for (int r = 0; r < 4; ++r) cp[(size_t)r * N] = acc[i][j][r];
    }
}

// ---------------- fused QKV GEMM: epilogue applies RoPE + layout -----------
__global__ __launch_bounds__(256) void gemm_qkv_rope(const uint16_t* __restrict__ A,
                                                     const uint16_t* __restrict__ B,
                                                     const float* __restrict__ cosT,
                                                     const float* __restrict__ sinT,
                                                     uint16_t* __restrict__ qr,
                                                     uint16_t* __restrict__ kr,
                                                     uint16_t* __restrict__ vT) {
  constexpr int K = DDIM;
  __shared__ uint16_t As[128 * 32];
  __shared__ uint16_t Bs[128 * 32];
  const int m0 = blockIdx.x * 128;
  const int n0 = blockIdx.y * 128;
  const int t = threadIdx.x;
  const int lane = t & 63;
  const int w = t >> 6;
  const int wr = w >> 1, wc = w & 1;
  const int srow = t >> 2;
  const int scol = (t & 3) * 8;
  const int c0 = lane & 15, c1 = lane >> 4;

  floatx4 acc[4][4];
#pragma unroll
  for (int i = 0; i < 4; ++i)
#pragma unroll
    for (int j = 0; j < 4; ++j) acc[i][j] = (floatx4){0.f, 0.f, 0.f, 0.f};

  for (int k0 = 0; k0 < K; k0 += 32) {
    const uint16_t* ga = A + (size_t)(m0 + srow) * K + k0 + scol;
    load_lds_16B(ga, &As[t * 8]);
    load_lds_16B(ga + (size_t)64 * K, &As[t * 8 + 64 * 32]);
    const uint16_t* gb = B + (size_t)(n0 + srow) * K + k0 + scol;
    load_lds_16B(gb, &Bs[t * 8]);
    load_lds_16B(gb + (size_t)64 * K, &Bs[t * 8 + 64 * 32]);
    __syncthreads();

    short8 a[4], b[4];
#pragma unroll
    for (int i = 0; i < 4; ++i)
      a[i] = *(const short8*)&As[(wr * 64 + i * 16 + c0) * 32 + c1 * 8];
#pragma unroll
    for (int j = 0; j < 4; ++j)
      b[j] = *(const short8*)&Bs[(wc * 64 + j * 16 + c0) * 32 + c1 * 8];
#pragma unroll
    for (int i = 0; i < 4; ++i)
#pragma unroll
      for (int j = 0; j < 4; ++j)
        acc[i][j] = __builtin_amdgcn_mfma_f32_16x16x32_bf16(a[i], b[j], acc[i][j], 0, 0, 0);
    __syncthreads();
  }

  // ---- epilogue: q/k rope'd, v transposed ----
#pragma unroll
  for (int j = 0; j < 4; ++j) {
    const int col = n0 + wc * 64 + j * 16 + c0;   // 0..3071
    const int sec = col >> 10;                    // 0=q 1=k 2=v
    const int e = col & 1023;
    const int h = e >> 6, dh = e & 63;
#pragma unroll
    for (int i = 0; i < 4; ++i) {
      const int row = m0 + wr * 64 + i * 16 + c1 * 4;  // b*L + l
      const int bb = row >> 11;
      const int l = row & 2047;
      if (sec == 2) {
        uint16_t* vp = vT + ((size_t)((bb * HDIM + h) * DH + dh)) * LDIM + l;
#pragma unroll
        for (int r = 0; r < 4; ++r) vp[r] = f2b(acc[i][j][r]);
      } else {
        const float sgn = (dh < 32) ? -1.f : 1.f;
        const float sc = (sec == 0) ? QSCALE : 1.f;
        uint16_t* dp = (sec == 0 ? qr : kr) + ((size_t)((bb * HDIM + h) * LDIM + l)) * DH + dh;
        const int fi = l * 32 + (dh & 31);
#pragma unroll
        for (int r = 0; r < 4; ++r) {
          float cv = cosT[fi + r * 32];
          float sv = sinT[fi + r * 32];
          float o = (acc[i][j][r] * cv + sgn * acc[i][j ^ 2][r] * sv) * sc;
          dp[(size_t)r * DH] = f2b(o);
        }
      }
    }
  }
}

// ---------------- flash attention, 32x32 MFMA, P via per-wave LDS ----------
// grid (L/128, H, B), 256 threads = 4 waves, each wave 32 q-rows.
// S^T = mfma32(K, Q): lane holds S[q=lane&31][kv=(r&3)+8*(r>>2)+4*(lane>>5)].
// Softmax lane-local; cross-half (hi) reductions via __shfl_xor(.,32)
// (proven in rounds 1-3; replaces the unverified raw-asm permlane32_swap
// that rounds 4/5 shared). P is written to a per-wave swizzled LDS tile at
// ABSOLUTE kv positions (HW-verified C/D formula) and read back contiguously
// as the PV B-fragment -> immune to A/B k-layout assumptions.
// O^T = mfma32(V^T, P^T). K,V in swizzled LDS, double-buffered.

__device__ __forceinline__ void attn_phase(
    const uint16_t* __restrict__ kt, const uint16_t* __restrict__ vt,
    uint16_t* __restrict__ pl,
    const int (&off)[2][4], const int (&pw)[8], const short8 (&qb)[4],
    float& m, float& lsum, floatx16& acc0, floatx16& acc1) {
  // ---- QK^T: two 32x32 S-tiles (kv 0-31, 32-63) ----
  floatx16 s0 = (floatx16){0.f,0.f,0.f,0.f,0.f,0.f,0.f,0.f,0.f,0.f,0.f,0.f,0.f,0.f,0.f,0.f};
  floatx16 s1 = s0;
  __builtin_amdgcn_s_setprio(1);
#pragma unroll
  for (int c = 0; c < 4; ++c) {
    short8 ka = *(const short8*)(kt + off[0][c]);
    s0 = __builtin_amdgcn_mfma_f32_32x32x16_bf16(ka, qb[c], s0, 0, 0, 0);
  }
#pragma unroll
  for (int c = 0; c < 4; ++c) {
    short8 ka = *(const short8*)(kt + off[1][c]);
    s1 = __builtin_amdgcn_mfma_f32_32x32x16_bf16(ka, qb[c], s1, 0, 0, 0);
  }
  __builtin_amdgcn_s_setprio(0);

  // ---- row max over 32 regs (q lane-local), then cross-half combine ----
  float x0 = max3f(s0[0], s0[1], s0[2]);
  float x1 = max3f(s0[3], s0[4], s0[5]);
  float x2 = max3f(s0[6], s0[7], s0[8]);
  float x3 = max3f(s0[9], s0[10], s0[11]);
  float x4 = max3f(s0[12], s0[13], s0[14]);
  float x5 = max3f(s0[15], s1[0], s1[1]);
  float x6 = max3f(s1[2], s1[3], s1[4]);
  float x7 = max3f(s1[5], s1[6], s1[7]);
  float x8 = max3f(s1[8], s1[9], s1[10]);
  float x9 = max3f(s1[11], s1[12], s1[13]);
  float xa = fmaxf(s1[14], s1[15]);
  float y0 = max3f(x0, x1, x2);
  float y1 = max3f(x3, x4, x5);
  float y2 = max3f(x6, x7, x8);
  float y3 = fmaxf(x9, xa);
  float tmax = fmaxf(max3f(y0, y1, y2), y3);
  tmax = fmaxf(tmax, __shfl_xor(tmax, 32));

  // ---- defer-max rescale (THR=8, log2 domain) ----
  if (__any(tmax > m + 8.f)) {
    float mn = fmaxf(m, tmax);
    float scl = __builtin_amdgcn_exp2f(m - mn);
    lsum *= scl;
#pragma unroll
    for (int r = 0; r < 16; ++r) { acc0[r] *= scl; acc1[r] *= scl; }
    m = mn;
  }

  // ---- exp2 + sum + pack to per-wave LDS at absolute kv positions ----
  // s0[4g+i] <-> kv = i + 8g + 4*hi ; s1[4g+i] <-> kv = 32 + i + 8g + 4*hi
  float ts = 0.f;
#pragma unroll
  for (int g = 0; g < 4; ++g) {
    float e0 = __builtin_amdgcn_exp2f(s0[4 * g + 0] - m);
    float e1 = __builtin_amdgcn_exp2f(s0[4 * g + 1] - m);
    float e2 = __builtin_amdgcn_exp2f(s0[4 * g + 2] - m);
    float e3 = __builtin_amdgcn_exp2f(s0[4 * g + 3] - m);
    ts += (e0 + e1) + (e2 + e3);
    *(uint2*)(pl + pw[g]) = make_uint2(cvtpk(e0, e1), cvtpk(e2, e3));
  }
#pragma unroll
  for (int g = 0; g < 4; ++g) {
    float e0 = __builtin_amdgcn_exp2f(s1[4 * g + 0] - m);
    float e1 = __builtin_amdgcn_exp2f(s1[4 * g + 1] - m);
    float e2 = __builtin_amdgcn_exp2f(s1[4 * g + 2] - m);
    float e3 = __builtin_amdgcn_exp2f(s1[4 * g + 3] - m);
    ts += (e0 + e1) + (e2 + e3);
    *(uint2*)(pl + pw[4 + g]) = make_uint2(cvtpk(e0, e1), cvtpk(e2, e3));
  }
  lsum += ts;

  // ---- read P back as contiguous B-fragments (same wave, lgkm-ordered) ----
  short8 pf0 = *(const short8*)(pl + off[0][0]);
  short8 pf1 = *(const short8*)(pl + off[0][1]);
  short8 pf2 = *(const short8*)(pl + off[0][2]);
  short8 pf3 = *(const short8*)(pl + off[0][3]);

  // ---- O^T += V^T . P^T ----
  __builtin_amdgcn_s_setprio(1);
#pragma unroll
  for (int d = 0; d < 2; ++d) {
    floatx16& ac = d ? acc1 : acc0;
    ac = __builtin_amdgcn_mfma_f32_32x32x16_bf16(*(const short8*)(vt + off[d][0]), pf0, ac, 0, 0, 0);
    ac = __builtin_amdgcn_mfma_f32_32x32x16_bf16(*(const short8*)(vt + off[d][1]), pf1, ac, 0, 0, 0);
    ac = __builtin_amdgcn_mfma_f32_32x32x16_bf16(*(const short8*)(vt + off[d][2]), pf2, ac, 0, 0, 0);
    ac = __builtin_amdgcn_mfma_f32_32x32x16_bf16(*(const short8*)(vt + off[d][3]), pf3, ac, 0, 0, 0);
  }
  __builtin_amdgcn_s_setprio(0);
}

__global__ __launch_bounds__(256) void attn(const uint16_t* __restrict__ qr,
                                            const uint16_t* __restrict__ kr,
                                            const uint16_t* __restrict__ vT,
                                            uint16_t* __restrict__ out) {
  __shared__ uint16_t KsA[2][64 * 64];
  __shared__ uint16_t VsA[2][64 * 64];
  __shared__ uint16_t Pl[4][32 * 64];
  const int t = threadIdx.x, lane = t & 63, w = t >> 6;
  const int l31 = lane & 31, hi = lane >> 5;
  const int b = blockIdx.z, h = blockIdx.y;
  const int bh = b * HDIM + h;
  const uint16_t* Qb = qr + (size_t)bh * LDIM * DH;
  const char* Kp = (const char*)(kr + (size_t)bh * LDIM * DH);
  const char* Vp = (const char*)(vT + (size_t)bh * DH * LDIM);
  uint16_t* pl = &Pl[w][0];

  // staging geometry
  const int srow = t >> 3;
  const int scsw = ((t & 7) * 16) ^ ((srow & 7) << 4);
  const char* kgs = Kp + (size_t)srow * 128 + scsw;
  const char* vgs = Vp + (size_t)srow * (LDIM * 2) + scsw;

#define STAGE(B, N) do {                                                         \
    load_lds_16B((const uint16_t*)(kgs + (size_t)(N) * 8192),            &KsA[B][t * 8]);        \
    load_lds_16B((const uint16_t*)(kgs + (size_t)(N) * 8192 + 4096),     &KsA[B][2048 + t * 8]); \
    load_lds_16B((const uint16_t*)(vgs + (size_t)(N) * 128),             &VsA[B][t * 8]);        \
    load_lds_16B((const uint16_t*)(vgs + (size_t)(N) * 128 + 2 * 32 * LDIM), &VsA[B][2048 + t * 8]); \
  } while (0)

  // Q B-fragments: lane holds Q[q0+l31][c*16 + hi*8 + j]
  const int q0 = blockIdx.x * 128 + w * 32;
  short8 qb[4];
#pragma unroll
  for (int c = 0; c < 4; ++c)
    qb[c] = *(const short8*)&Qb[(size_t)(q0 + l31) * DH + c * 16 + hi * 8];

  // LDS fragment offsets (elements): row-block x, k-chunk c (shared K/V/P-read)
  const int swz = (l31 & 7) << 4;
  int off[2][4];
#pragma unroll
  for (int x = 0; x < 2; ++x)
#pragma unroll
    for (int c = 0; c < 4; ++c)
      off[x][c] = (x * 32 + l31) * 64 + (((c * 32 + hi * 16) ^ swz) >> 1);

  // P-write offsets (elements): group g covers kv {8g+4hi .. +3} (+32 for s1)
  int pw[8];
#pragma unroll
  for (int g = 0; g < 4; ++g) {
    pw[g]     = l31 * 64 + (((g * 16 + hi * 8) ^ swz) >> 1);
    pw[4 + g] = l31 * 64 + (((64 + g * 16 + hi * 8) ^ swz) >> 1);
  }

  float m = -1e30f, lsum = 0.f;
  floatx16 acc0 = (floatx16){0.f,0.f,0.f,0.f,0.f,0.f,0.f,0.f,0.f,0.f,0.f,0.f,0.f,0.f,0.f,0.f};
  floatx16 acc1 = acc0;

  STAGE(0, 0);
  __syncthreads();

#pragma unroll 1
  for (int ii = 0; ii < 16; ++ii) {
    STAGE(1, 2 * ii + 1);
    attn_phase(&KsA[0][0], &VsA[0][0], pl, off, pw, qb, m, lsum, acc0, acc1);
    __syncthreads();
    if (ii < 15) STAGE(0, 2 * ii + 2);
    attn_phase(&KsA[1][0], &VsA[1][0], pl, off, pw, qb, m, lsum, acc0, acc1);
    __syncthreads();
  }
#undef STAGE

  // ---- finalize: cross-half lsum combine, normalize, store ----
  float ltot = lsum + __shfl_xor(lsum, 32);
  float inv = 1.f / ltot;
  size_t orow = (size_t)(b * LDIM) + blockIdx.x * 128 + w * 32 + l31;
  uint16_t* op = out + orow * DDIM + h * DH;
#pragma unroll
  for (int g = 0; g < 4; ++g) {
    *(uint2*)&op[8 * g + 4 * hi] =
        make_uint2(cvtpk(acc0[4 * g] * inv, acc0[4 * g + 1] * inv),
                   cvtpk(acc0[4 * g + 2] * inv, acc0[4 * g + 3] * inv));
    *(uint2*)&op[32 + 8 * g + 4 * hi] =
        make_uint2(cvtpk(acc1[4 * g] * inv, acc1[4 * g + 1] * inv),
                   cvtpk(acc1[4 * g + 2] * inv, acc1[4 * g + 3] * inv));
  }
}

// ---------------- workspace layout -----------------------------------------
static constexpr size_t OFF_XB    = 0;                   // 8 MB bf16 x
static constexpr size_t OFF_WQKVB = (size_t)8 << 20;     // 6 MB
static constexpr size_t OFF_WOUTB = (size_t)14 << 20;    // 2 MB
static constexpr size_t OFF_QR    = (size_t)16 << 20;    // 8 MB
static constexpr size_t OFF_KR    = (size_t)24 << 20;    // 8 MB
static constexpr size_t OFF_VT    = (size_t)32 << 20;    // 8 MB
static constexpr size_t OFF_AO    = (size_t)40 << 20;    // 8 MB
static constexpr size_t OFF_COS   = (size_t)48 << 20;    // 256 KB
static constexpr size_t OFF_SIN   = OFF_COS + ((size_t)256 << 10);

extern "C" void kernel_launch(void* const* d_in, const int* in_sizes, int n_in,
                              void* d_out, int out_size, void* d_ws, size_t ws_size,
                              hipStream_t stream) {
  const float* x     = (const float*)d_in[0];
  const float* w_qkv = (const float*)d_in[1];
  const float* w_out = (const float*)d_in[2];
  float* out = (float*)d_out;
  char* ws = (char*)d_ws;

  uint16_t* xb    = (uint16_t*)(ws + OFF_XB);
  uint16_t* wqkvb = (uint16_t*)(ws + OFF_WQKVB);
  uint16_t* woutb = (uint16_t*)(ws + OFF_WOUTB);
  uint16_t* qr    = (uint16_t*)(ws + OFF_QR);
  uint16_t* kr    = (uint16_t*)(ws + OFF_KR);
  uint16_t* vT    = (uint16_t*)(ws + OFF_VT);
  uint16_t* ao    = (uint16_t*)(ws + OFF_AO);
  float*    cosT  = (float*)(ws + OFF_COS);
  float*    sinT  = (float*)(ws + OFF_SIN);

  cvt_bf16_x4<<<(ML * DDIM / 4 + 255) / 256, 256, 0, stream>>>(x, xb, ML * DDIM / 4);
  cvt_bf16_x4<<<(3 * DDIM * DDIM / 4 + 255) / 256, 256, 0, stream>>>(w_qkv, wqkvb, 3 * DDIM * DDIM / 4);
  cvt_bf16_x4<<<(DDIM * DDIM / 4 + 255) / 256, 256, 0, stream>>>(w_out, woutb, DDIM * DDIM / 4);
  rope_table<<<(LDIM * 32) / 256, 256, 0, stream>>>(cosT, sinT);

  // fused QKV projection + RoPE + V-transpose
  gemm_qkv_rope<<<dim3(ML / 128, 3 * DDIM / 128), 256, 0, stream>>>(xb, wqkvb, cosT, sinT, qr, kr, vT);

  // attention
  attn<<<dim3(LDIM / 128, HDIM, BDIM), 256, 0, stream>>>(qr, kr, vT, ao);

  // output projection
  gemm_bt<<<dim3(ML / 128, DDIM / 128), 256, 0, stream>>>(ao, woutb, out, ML, DDIM, DDIM);
}

// Round 8
// 129.984 us; speedup vs baseline: 2.4944x; 1.1366x over previous
//
#include <hip/hip_runtime.h>
#include <hip/hip_bf16.h>
#include <stdint.h>

// ---------------------------------------------------------------------------
// RoPE self-attention, B=2 L=2048 D=1024 H=16 Dh=64, f32 in/out, bf16 MFMA core
// ---------------------------------------------------------------------------

typedef __attribute__((ext_vector_type(8))) short short8;
typedef __attribute__((ext_vector_type(4))) float floatx4;
typedef __attribute__((ext_vector_type(16))) float floatx16;

#define BDIM 2
#define LDIM 2048
#define DDIM 1024
#define HDIM 16
#define DH 64
#define ML (BDIM * LDIM)   // 4096 rows

// log2(e) * (1/sqrt(Dh)) folded into Q at the producer -> attn softmax runs
// in exp2 domain with no per-element scaling.
#define QSCALE 0.18033688011112042f

// f32 -> bf16 round-to-nearest-even
__device__ __forceinline__ uint16_t f2b(float x) {
  uint32_t b = __float_as_uint(x);
  b += 0x7FFFu + ((b >> 16) & 1u);
  return (uint16_t)(b >> 16);
}

__device__ __forceinline__ uint32_t pack2(float a, float b) {
  return (uint32_t)f2b(a) | ((uint32_t)f2b(b) << 16);
}

// packed f32x2 -> bf16x2 in one instruction (RNE)
__device__ __forceinline__ uint32_t cvtpk(float lo, float hi) {
  uint32_t r;
  asm("v_cvt_pk_bf16_f32 %0, %1, %2" : "=v"(r) : "v"(lo), "v"(hi));
  return r;
}

__device__ __forceinline__ float max3f(float a, float b, float c) {
  return fmaxf(fmaxf(a, b), c);
}

__device__ __forceinline__ void load_lds_16B(const uint16_t* g, uint16_t* l) {
  __builtin_amdgcn_global_load_lds(
      (const __attribute__((address_space(1))) void*)g,
      (__attribute__((address_space(3))) void*)l, 16, 0, 0);
}

// counted-vmcnt barrier pair (T4), PROPERLY FENCED (rule #18/#21):
// bare s_barrier is NOT a compiler memory fence -> without the
// sched_barrier(0)+""-asm pins, LDS DMA writes / ds_reads can be scheduled
// across it (the round-7 race). sched_barrier(0) emits no instructions.
#define WAIT_BAR(N) do {                                         \
    asm volatile("s_waitcnt vmcnt(" #N ")" ::: "memory");        \
    __builtin_amdgcn_sched_barrier(0);                           \
    __builtin_amdgcn_s_barrier();                                \
    asm volatile("" ::: "memory");                               \
    __builtin_amdgcn_sched_barrier(0);                           \
  } while (0)

// ---------------- fused prep: 3 converts + rope table, one launch ----------
__global__ void prep(const float* __restrict__ x, const float* __restrict__ wqkv,
                     const float* __restrict__ wout,
                     uint16_t* __restrict__ xb, uint16_t* __restrict__ wqkvb,
                     uint16_t* __restrict__ woutb,
                     float* __restrict__ cosT, float* __restrict__ sinT) {
  const int N0 = ML * DDIM / 4;           // 1048576
  const int N1 = 3 * DDIM * DDIM / 4;     // 786432
  const int N2 = DDIM * DDIM / 4;         // 262144
  int id = blockIdx.x * 256 + threadIdx.x;
  if (id < N0) {
    float4 v = ((const float4*)x)[id];
    ((uint2*)xb)[id] = make_uint2(pack2(v.x, v.y), pack2(v.z, v.w));
  } else if (id < N0 + N1) {
    int i = id - N0;
    float4 v = ((const float4*)wqkv)[i];
    ((uint2*)wqkvb)[i] = make_uint2(pack2(v.x, v.y), pack2(v.z, v.w));
  } else if (id < N0 + N1 + N2) {
    int i = id - N0 - N1;
    float4 v = ((const float4*)wout)[i];
    ((uint2*)woutb)[i] = make_uint2(pack2(v.x, v.y), pack2(v.z, v.w));
  } else {
    int i = id - N0 - N1 - N2;            // 0..65535 = L*32
    int l = i >> 5, f = i & 31;
    float invf = exp2f(-(float)f * (13.287712379549449f / 32.f));
    float ang = (float)l * invf;
    cosT[i] = cosf(ang);
    sinT[i] = sinf(ang);
  }
}

// ---------------- GEMM compute step (shared by both GEMMs) -----------------
__device__ __forceinline__ void gemm_step(const uint16_t* __restrict__ as,
                                          const uint16_t* __restrict__ bs,
                                          int wr, int wc, int c0, int c1,
                                          floatx4 (&acc)[4][4]) {
  short8 a[4], b[4];
#pragma unroll
  for (int i = 0; i < 4; ++i)
    a[i] = *(const short8*)&as[(wr * 64 + i * 16 + c0) * 32 + c1 * 8];
#pragma unroll
  for (int j = 0; j < 4; ++j)
    b[j] = *(const short8*)&bs[(wc * 64 + j * 16 + c0) * 32 + c1 * 8];
#pragma unroll
  for (int i = 0; i < 4; ++i)
#pragma unroll
    for (int j = 0; j < 4; ++j)
      acc[i][j] = __builtin_amdgcn_mfma_f32_16x16x32_bf16(a[i], b[j], acc[i][j], 0, 0, 0);
}

#define GEMM_STAGE(BUF, K0) do {                                              \
    const uint16_t* ga = A + (size_t)(m0 + srow) * K + (K0) + scol;           \
    load_lds_16B(ga, &As[(BUF) * 4096 + t * 8]);                              \
    load_lds_16B(ga + (size_t)64 * K, &As[(BUF) * 4096 + 2048 + t * 8]);      \
    const uint16_t* gb = Bm + (size_t)(n0 + srow) * K + (K0) + scol;          \
    load_lds_16B(gb, &Bs[(BUF) * 4096 + t * 8]);                              \
    load_lds_16B(gb + (size_t)64 * K, &Bs[(BUF) * 4096 + 2048 + t * 8]);      \
  } while (0)

// ---------------- plain GEMM (bt) for the output projection ----------------
// C[m][n] = sum_k A[m][k]*B[n][k]; 128x128 tile, BK=32, triple-buffered LDS,
// counted-vmcnt pipeline (loads issued 2 tiles ahead).
__global__ __launch_bounds__(256) void gemm_bt(const uint16_t* __restrict__ A,
                                               const uint16_t* __restrict__ Bm,
                                               float* __restrict__ C,
                                               int M, int N, int K) {
  __shared__ uint16_t As[3 * 4096];
  __shared__ uint16_t Bs[3 * 4096];
  const int m0 = blockIdx.x * 128;
  const int n0 = blockIdx.y * 128;
  const int t = threadIdx.x;
  const int lane = t & 63;
  const int w = t >> 6;
  const int wr = w >> 1, wc = w & 1;
  const int srow = t >> 2;
  const int scol = (t & 3) * 8;
  const int c0 = lane & 15, c1 = lane >> 4;

  floatx4 acc[4][4];
#pragma unroll
  for (int i = 0; i < 4; ++i)
#pragma unroll
    for (int j = 0; j < 4; ++j) acc[i][j] = (floatx4){0.f, 0.f, 0.f, 0.f};

  const int nk = K >> 5;
  GEMM_STAGE(0, 0);
  GEMM_STAGE(1, 32);
#pragma unroll 1
  for (int ki = 0; ki < nk - 1; ++ki) {
    WAIT_BAR(4);
    if (ki + 2 < nk) GEMM_STAGE((ki + 2) % 3, (ki + 2) * 32);
    gemm_step(&As[(ki % 3) * 4096], &Bs[(ki % 3) * 4096], wr, wc, c0, c1, acc);
  }
  WAIT_BAR(0);
  gemm_step(&As[((nk - 1) % 3) * 4096], &Bs[((nk - 1) % 3) * 4096], wr, wc, c0, c1, acc);

#pragma unroll
  for (int i = 0; i < 4; ++i)
#pragma unroll
    for (int j = 0; j < 4; ++j) {
      int row = m0 + wr * 64 + i * 16 + c1 * 4;
      int col = n0 + wc * 64 + j * 16 + c0;
      float* cp = C + (size_t)row * N + col;
#pragma unroll
      for (int r = 0; r < 4; ++r) cp[(size_t)r * N] = acc[i][j][r];
    }
}

// ---------------- fused QKV GEMM: epilogue applies RoPE + layout -----------
__global__ __launch_bounds__(256) void gemm_qkv_rope(const uint16_t* __restrict__ A,
                                                     const uint16_t* __restrict__ Bm,
                                                     const float* __restrict__ cosT,
                                                     const float* __restrict__ sinT,
                                                     uint16_t* __restrict__ qr,
                                                     uint16_t* __restrict__ kr,
                                                     uint16_t* __restrict__ vT) {
  constexpr int K = DDIM;
  __shared__ uint16_t As[3 * 4096];
  __shared__ uint16_t Bs[3 * 4096];
  const int m0 = blockIdx.x * 128;
  const int n0 = blockIdx.y * 128;
  const int t = threadIdx.x;
  const int lane = t & 63;
  const int w = t >> 6;
  const int wr = w >> 1, wc = w & 1;
  const int srow = t >> 2;
  const int scol = (t & 3) * 8;
  const int c0 = lane & 15, c1 = lane >> 4;

  floatx4 acc[4][4];
#pragma unroll
  for (int i = 0; i < 4; ++i)
#pragma unroll
    for (int j = 0; j < 4; ++j) acc[i][j] = (floatx4){0.f, 0.f, 0.f, 0.f};

  const int nk = K >> 5;  // 32
  GEMM_STAGE(0, 0);
  GEMM_STAGE(1, 32);
#pragma unroll 1
  for (int ki = 0; ki < nk - 1; ++ki) {
    WAIT_BAR(4);
    if (ki + 2 < nk) GEMM_STAGE((ki + 2) % 3, (ki + 2) * 32);
    gemm_step(&As[(ki % 3) * 4096], &Bs[(ki % 3) * 4096], wr, wc, c0, c1, acc);
  }
  WAIT_BAR(0);
  gemm_step(&As[((nk - 1) % 3) * 4096], &Bs[((nk - 1) % 3) * 4096], wr, wc, c0, c1, acc);

  // ---- epilogue: q/k rope'd, v transposed ----
#pragma unroll
  for (int j = 0; j < 4; ++j) {
    const int col = n0 + wc * 64 + j * 16 + c0;   // 0..3071
    const int sec = col >> 10;                    // 0=q 1=k 2=v
    const int e = col & 1023;
    const int h = e >> 6, dh = e & 63;
#pragma unroll
    for (int i = 0; i < 4; ++i) {
      const int row = m0 + wr * 64 + i * 16 + c1 * 4;  // b*L + l
      const int bb = row >> 11;
      const int l = row & 2047;
      if (sec == 2) {
        uint16_t* vp = vT + ((size_t)((bb * HDIM + h) * DH + dh)) * LDIM + l;
#pragma unroll
        for (int r = 0; r < 4; ++r) vp[r] = f2b(acc[i][j][r]);
      } else {
        const float sgn = (dh < 32) ? -1.f : 1.f;
        const float sc = (sec == 0) ? QSCALE : 1.f;
        uint16_t* dp = (sec == 0 ? qr : kr) + ((size_t)((bb * HDIM + h) * LDIM + l)) * DH + dh;
        const int fi = l * 32 + (dh & 31);
#pragma unroll
        for (int r = 0; r < 4; ++r) {
          float cv = cosT[fi + r * 32];
          float sv = sinT[fi + r * 32];
          float o = (acc[i][j][r] * cv + sgn * acc[i][j ^ 2][r] * sv) * sc;
          dp[(size_t)r * DH] = f2b(o);
        }
      }
    }
  }
}

// ---------------- flash attention, 32x32 MFMA, P via per-wave LDS ----------
// grid 512 (XCD-chunk-swizzled 1D), 256 threads = 4 waves, each wave 32 q-rows.
// S^T = mfma32(K, Q): lane holds S[q=lane&31][kv=(r&3)+8*(r>>2)+4*(lane>>5)].
// Softmax lane-local; cross-half reductions via __shfl_xor(.,32). P written
// to per-wave swizzled LDS at ABSOLUTE kv positions, read back contiguously.
// O^T = mfma32(V^T, P^T). K,V triple-buffered LDS, counted-vmcnt pipeline.

__device__ __forceinline__ void attn_phase(
    const uint16_t* __restrict__ kt, const uint16_t* __restrict__ vt,
    uint16_t* __restrict__ pl,
    const int (&off)[2][4], const int (&pw)[8], const short8 (&qb)[4],
    float& m, float& lsum, floatx16& acc0, floatx16& acc1) {
  // ---- QK^T: two 32x32 S-tiles (kv 0-31, 32-63) ----
  floatx16 s0 = (floatx16){0.f,0.f,0.f,0.f,0.f,0.f,0.f,0.f,0.f,0.f,0.f,0.f,0.f,0.f,0.f,0.f};
  floatx16 s1 = s0;
  __builtin_amdgcn_s_setprio(1);
#pragma unroll
  for (int c = 0; c < 4; ++c) {
    short8 ka = *(const short8*)(kt + off[0][c]);
    s0 = __builtin_amdgcn_mfma_f32_32x32x16_bf16(ka, qb[c], s0, 0, 0, 0);
  }
#pragma unroll
  for (int c = 0; c < 4; ++c) {
    short8 ka = *(const short8*)(kt + off[1][c]);
    s1 = __builtin_amdgcn_mfma_f32_32x32x16_bf16(ka, qb[c], s1, 0, 0, 0);
  }
  __builtin_amdgcn_s_setprio(0);

  // ---- row max over 32 regs (q lane-local), then cross-half combine ----
  float x0 = max3f(s0[0], s0[1], s0[2]);
  float x1 = max3f(s0[3], s0[4], s0[5]);
  float x2 = max3f(s0[6], s0[7], s0[8]);
  float x3 = max3f(s0[9], s0[10], s0[11]);
  float x4 = max3f(s0[12], s0[13], s0[14]);
  float x5 = max3f(s0[15], s1[0], s1[1]);
  float x6 = max3f(s1[2], s1[3], s1[4]);
  float x7 = max3f(s1[5], s1[6], s1[7]);
  float x8 = max3f(s1[8], s1[9], s1[10]);
  float x9 = max3f(s1[11], s1[12], s1[13]);
  float xa = fmaxf(s1[14], s1[15]);
  float y0 = max3f(x0, x1, x2);
  float y1 = max3f(x3, x4, x5);
  float y2 = max3f(x6, x7, x8);
  float y3 = fmaxf(x9, xa);
  float tmax = fmaxf(max3f(y0, y1, y2), y3);
  tmax = fmaxf(tmax, __shfl_xor(tmax, 32));

  // ---- defer-max rescale (THR=8, log2 domain) ----
  if (__any(tmax > m + 8.f)) {
    float mn = fmaxf(m, tmax);
    float scl = __builtin_amdgcn_exp2f(m - mn);
    lsum *= scl;
#pragma unroll
    for (int r = 0; r < 16; ++r) { acc0[r] *= scl; acc1[r] *= scl; }
    m = mn;
  }

  // ---- exp2 + sum + pack to per-wave LDS at absolute kv positions ----
  float ts = 0.f;
#pragma unroll
  for (int g = 0; g < 4; ++g) {
    float e0 = __builtin_amdgcn_exp2f(s0[4 * g + 0] - m);
    float e1 = __builtin_amdgcn_exp2f(s0[4 * g + 1] - m);
    float e2 = __builtin_amdgcn_exp2f(s0[4 * g + 2] - m);
    float e3 = __builtin_amdgcn_exp2f(s0[4 * g + 3] - m);
    ts += (e0 + e1) + (e2 + e3);
    *(uint2*)(pl + pw[g]) = make_uint2(cvtpk(e0, e1), cvtpk(e2, e3));
  }
#pragma unroll
  for (int g = 0; g < 4; ++g) {
    float e0 = __builtin_amdgcn_exp2f(s1[4 * g + 0] - m);
    float e1 = __builtin_amdgcn_exp2f(s1[4 * g + 1] - m);
    float e2 = __builtin_amdgcn_exp2f(s1[4 * g + 2] - m);
    float e3 = __builtin_amdgcn_exp2f(s1[4 * g + 3] - m);
    ts += (e0 + e1) + (e2 + e3);
    *(uint2*)(pl + pw[4 + g]) = make_uint2(cvtpk(e0, e1), cvtpk(e2, e3));
  }
  lsum += ts;

  // ---- read P back as contiguous B-fragments (same wave, lgkm-ordered) ----
  short8 pf0 = *(const short8*)(pl + off[0][0]);
  short8 pf1 = *(const short8*)(pl + off[0][1]);
  short8 pf2 = *(const short8*)(pl + off[0][2]);
  short8 pf3 = *(const short8*)(pl + off[0][3]);

  // ---- O^T += V^T . P^T ----
  __builtin_amdgcn_s_setprio(1);
#pragma unroll
  for (int d = 0; d < 2; ++d) {
    floatx16& ac = d ? acc1 : acc0;
    ac = __builtin_amdgcn_mfma_f32_32x32x16_bf16(*(const short8*)(vt + off[d][0]), pf0, ac, 0, 0, 0);
    ac = __builtin_amdgcn_mfma_f32_32x32x16_bf16(*(const short8*)(vt + off[d][1]), pf1, ac, 0, 0, 0);
    ac = __builtin_amdgcn_mfma_f32_32x32x16_bf16(*(const short8*)(vt + off[d][2]), pf2, ac, 0, 0, 0);
    ac = __builtin_amdgcn_mfma_f32_32x32x16_bf16(*(const short8*)(vt + off[d][3]), pf3, ac, 0, 0, 0);
  }
  __builtin_amdgcn_s_setprio(0);
}

__global__ __launch_bounds__(256) void attn(const uint16_t* __restrict__ qr,
                                            const uint16_t* __restrict__ kr,
                                            const uint16_t* __restrict__ vT,
                                            uint16_t* __restrict__ out) {
  __shared__ uint16_t KsA[3 * 4096];
  __shared__ uint16_t VsA[3 * 4096];
  __shared__ uint16_t Pl[4][2048];
  const int t = threadIdx.x, lane = t & 63, w = t >> 6;
  const int l31 = lane & 31, hi = lane >> 5;

  // XCD-chunk swizzle (512 % 8 == 0 -> bijective): blocks of one head
  // stay on one XCD's L2.
  const int id = blockIdx.x;
  const int sw = (id & 7) * 64 + (id >> 3);
  const int bx = sw & 15;            // L-tile
  const int h = (sw >> 4) & 15;
  const int b = sw >> 8;

  const int bh = b * HDIM + h;
  const uint16_t* Qb = qr + (size_t)bh * LDIM * DH;
  const char* Kp = (const char*)(kr + (size_t)bh * LDIM * DH);
  const char* Vp = (const char*)(vT + (size_t)bh * DH * LDIM);
  uint16_t* pl = &Pl[w][0];

  // staging geometry
  const int srow = t >> 3;
  const int scsw = ((t & 7) * 16) ^ ((srow & 7) << 4);
  const char* kgs = Kp + (size_t)srow * 128 + scsw;
  const char* vgs = Vp + (size_t)srow * (LDIM * 2) + scsw;

#define STAGE(BUF, N) do {                                                     \
    uint16_t* kd = &KsA[(BUF) * 4096];                                         \
    uint16_t* vd = &VsA[(BUF) * 4096];                                         \
    load_lds_16B((const uint16_t*)(kgs + (size_t)(N) * 8192), &kd[t * 8]);     \
    load_lds_16B((const uint16_t*)(kgs + (size_t)(N) * 8192 + 4096), &kd[2048 + t * 8]); \
    load_lds_16B((const uint16_t*)(vgs + (size_t)(N) * 128), &vd[t * 8]);      \
    load_lds_16B((const uint16_t*)(vgs + (size_t)(N) * 128 + 2 * 32 * LDIM), &vd[2048 + t * 8]); \
  } while (0)

  // Q B-fragments: lane holds Q[q0+l31][c*16 + hi*8 + j]
  const int q0 = bx * 128 + w * 32;
  short8 qb[4];
#pragma unroll
  for (int c = 0; c < 4; ++c)
    qb[c] = *(const short8*)&Qb[(size_t)(q0 + l31) * DH + c * 16 + hi * 8];

  // LDS fragment offsets (elements): row-block x, k-chunk c (shared K/V/P-read)
  const int swz = (l31 & 7) << 4;
  int off[2][4];
#pragma unroll
  for (int x = 0; x < 2; ++x)
#pragma unroll
    for (int c = 0; c < 4; ++c)
      off[x][c] = (x * 32 + l31) * 64 + (((c * 32 + hi * 16) ^ swz) >> 1);

  // P-write offsets (elements): group g covers kv {8g+4hi .. +3} (+32 for s1)
  int pw[8];
#pragma unroll
  for (int g = 0; g < 4; ++g) {
    pw[g]     = l31 * 64 + (((g * 16 + hi * 8) ^ swz) >> 1);
    pw[4 + g] = l31 * 64 + (((64 + g * 16 + hi * 8) ^ swz) >> 1);
  }

  float m = -1e30f, lsum = 0.f;
  floatx16 acc0 = (floatx16){0.f,0.f,0.f,0.f,0.f,0.f,0.f,0.f,0.f,0.f,0.f,0.f,0.f,0.f,0.f,0.f};
  floatx16 acc1 = acc0;

  // triple-buffered pipeline: loads issued 2 tiles ahead, counted vmcnt
  STAGE(0, 0);
  STAGE(1, 1);
#pragma unroll 1
  for (int n = 0; n < 31; ++n) {
    WAIT_BAR(4);
    if (n + 2 < 32) STAGE((n + 2) % 3, n + 2);
    attn_phase(&KsA[(n % 3) * 4096], &VsA[(n % 3) * 4096], pl, off, pw, qb,
               m, lsum, acc0, acc1);
  }
  WAIT_BAR(0);
  attn_phase(&KsA[(31 % 3) * 4096], &VsA[(31 % 3) * 4096], pl, off, pw, qb,
             m, lsum, acc0, acc1);
#undef STAGE

  // ---- finalize: cross-half lsum combine, normalize, store ----
  float ltot = lsum + __shfl_xor(lsum, 32);
  float inv = 1.f / ltot;
  size_t orow = (size_t)(b * LDIM) + bx * 128 + w * 32 + l31;
  uint16_t* op = out + orow * DDIM + h * DH;
#pragma unroll
  for (int g = 0; g < 4; ++g) {
    *(uint2*)&op[8 * g + 4 * hi] =
        make_uint2(cvtpk(acc0[4 * g] * inv, acc0[4 * g + 1] * inv),
                   cvtpk(acc0[4 * g + 2] * inv, acc0[4 * g + 3] * inv));
    *(uint2*)&op[32 + 8 * g + 4 * hi] =
        make_uint2(cvtpk(acc1[4 * g] * inv, acc1[4 * g + 1] * inv),
                   cvtpk(acc1[4 * g + 2] * inv, acc1[4 * g + 3] * inv));
  }
}

// ---------------- workspace layout -----------------------------------------
static constexpr size_t OFF_XB    = 0;                   // 8 MB bf16 x
static constexpr size_t OFF_WQKVB = (size_t)8 << 20;     // 6 MB
static constexpr size_t OFF_WOUTB = (size_t)14 << 20;    // 2 MB
static constexpr size_t OFF_QR    = (size_t)16 << 20;    // 8 MB
static constexpr size_t OFF_KR    = (size_t)24 << 20;    // 8 MB
static constexpr size_t OFF_VT    = (size_t)32 << 20;    // 8 MB
static constexpr size_t OFF_AO    = (size_t)40 << 20;    // 8 MB
static constexpr size_t OFF_COS   = (size_t)48 << 20;    // 256 KB
static constexpr size_t OFF_SIN   = OFF_COS + ((size_t)256 << 10);

extern "C" void kernel_launch(void* const* d_in, const int* in_sizes, int n_in,
                              void* d_out, int out_size, void* d_ws, size_t ws_size,
                              hipStream_t stream) {
  const float* x     = (const float*)d_in[0];
  const float* w_qkv = (const float*)d_in[1];
  const float* w_out = (const float*)d_in[2];
  float* out = (float*)d_out;
  char* ws = (char*)d_ws;

  uint16_t* xb    = (uint16_t*)(ws + OFF_XB);
  uint16_t* wqkvb = (uint16_t*)(ws + OFF_WQKVB);
  uint16_t* woutb = (uint16_t*)(ws + OFF_WOUTB);
  uint16_t* qr    = (uint16_t*)(ws + OFF_QR);
  uint16_t* kr    = (uint16_t*)(ws + OFF_KR);
  uint16_t* vT    = (uint16_t*)(ws + OFF_VT);
  uint16_t* ao    = (uint16_t*)(ws + OFF_AO);
  float*    cosT  = (float*)(ws + OFF_COS);
  float*    sinT  = (float*)(ws + OFF_SIN);

  // fused converts + rope table (one launch)
  prep<<<8448, 256, 0, stream>>>(x, w_qkv, w_out, xb, wqkvb, woutb, cosT, sinT);

  // fused QKV projection + RoPE + V-transpose
  gemm_qkv_rope<<<dim3(ML / 128, 3 * DDIM / 128), 256, 0, stream>>>(xb, wqkvb, cosT, sinT, qr, kr, vT);

  // attention (1D swizzled grid)
  attn<<<512, 256, 0, stream>>>(qr, kr, vT, ao);

  // output projection
  gemm_bt<<<dim3(ML / 128, DDIM / 128), 256, 0, stream>>>(ao, woutb, out, ML, DDIM, DDIM);
}

// Round 9
// 122.869 us; speedup vs baseline: 2.6389x; 1.0579x over previous
//
#include <hip/hip_runtime.h>
#include <hip/hip_bf16.h>
#include <stdint.h>

// ---------------------------------------------------------------------------
// RoPE self-attention, B=2 L=2048 D=1024 H=16 Dh=64, f32 in/out, bf16 MFMA core
// ---------------------------------------------------------------------------

typedef __attribute__((ext_vector_type(8))) short short8;
typedef __attribute__((ext_vector_type(4))) float floatx4;
typedef __attribute__((ext_vector_type(16))) float floatx16;
typedef __attribute__((ext_vector_type(4))) int intx4;

#define BDIM 2
#define LDIM 2048
#define DDIM 1024
#define HDIM 16
#define DH 64
#define ML (BDIM * LDIM)   // 4096 rows

// log2(e) * (1/sqrt(Dh)) folded into Q at the producer -> attn softmax runs
// in exp2 domain with no per-element scaling.
#define QSCALE 0.18033688011112042f

// f32 -> bf16 round-to-nearest-even
__device__ __forceinline__ uint16_t f2b(float x) {
  uint32_t b = __float_as_uint(x);
  b += 0x7FFFu + ((b >> 16) & 1u);
  return (uint16_t)(b >> 16);
}

__device__ __forceinline__ uint32_t pack2(float a, float b) {
  return (uint32_t)f2b(a) | ((uint32_t)f2b(b) << 16);
}

// packed f32x2 -> bf16x2 in one instruction (RNE)
__device__ __forceinline__ uint32_t cvtpk(float lo, float hi) {
  uint32_t r;
  asm("v_cvt_pk_bf16_f32 %0, %1, %2" : "=v"(r) : "v"(lo), "v"(hi));
  return r;
}

// exchange a.upper32lanes <-> b.lower32lanes (documented gfx950 semantics;
// pairing below matches the guide's HW-verified §B recipe). Distinct SSA
// values with both results live -> distinct registers (no aliasing hazard).
#define PLSWAP(a, b) asm("v_permlane32_swap_b32 %0, %1" : "+v"(a), "+v"(b))

__device__ __forceinline__ float max3f(float a, float b, float c) {
  return fmaxf(fmaxf(a, b), c);
}

__device__ __forceinline__ void load_lds_16B(const uint16_t* g, uint16_t* l) {
  __builtin_amdgcn_global_load_lds(
      (const __attribute__((address_space(1))) void*)g,
      (__attribute__((address_space(3))) void*)l, 16, 0, 0);
}

// counted-vmcnt barrier pair (T4), fenced (rule #18/#21): bare s_barrier is
// NOT a compiler memory fence; sched_barrier(0) pins (no instructions).
#define WAIT_BAR(N) do {                                         \
    asm volatile("s_waitcnt vmcnt(" #N ")" ::: "memory");        \
    __builtin_amdgcn_sched_barrier(0);                           \
    __builtin_amdgcn_s_barrier();                                \
    asm volatile("" ::: "memory");                               \
    __builtin_amdgcn_sched_barrier(0);                           \
  } while (0)

union I4S8 { intx4 i; short8 s; };

// ---------------- fused prep: 3 converts + rope table, one launch ----------
__global__ void prep(const float* __restrict__ x, const float* __restrict__ wqkv,
                     const float* __restrict__ wout,
                     uint16_t* __restrict__ xb, uint16_t* __restrict__ wqkvb,
                     uint16_t* __restrict__ woutb,
                     float* __restrict__ cosT, float* __restrict__ sinT) {
  const int N0 = ML * DDIM / 4;           // 1048576
  const int N1 = 3 * DDIM * DDIM / 4;     // 786432
  const int N2 = DDIM * DDIM / 4;         // 262144
  int id = blockIdx.x * 256 + threadIdx.x;
  if (id < N0) {
    float4 v = ((const float4*)x)[id];
    ((uint2*)xb)[id] = make_uint2(pack2(v.x, v.y), pack2(v.z, v.w));
  } else if (id < N0 + N1) {
    int i = id - N0;
    float4 v = ((const float4*)wqkv)[i];
    ((uint2*)wqkvb)[i] = make_uint2(pack2(v.x, v.y), pack2(v.z, v.w));
  } else if (id < N0 + N1 + N2) {
    int i = id - N0 - N1;
    float4 v = ((const float4*)wout)[i];
    ((uint2*)woutb)[i] = make_uint2(pack2(v.x, v.y), pack2(v.z, v.w));
  } else {
    int i = id - N0 - N1 - N2;            // 0..65535 = L*32
    int l = i >> 5, f = i & 31;
    float invf = exp2f(-(float)f * (13.287712379549449f / 32.f));
    float ang = (float)l * invf;
    cosT[i] = cosf(ang);
    sinT[i] = sinf(ang);
  }
}

// ---------------- GEMM compute step (shared by both GEMMs) -----------------
__device__ __forceinline__ void gemm_step(const uint16_t* __restrict__ as,
                                          const uint16_t* __restrict__ bs,
                                          int wr, int wc, int c0, int c1,
                                          floatx4 (&acc)[4][4]) {
  short8 a[4], b[4];
#pragma unroll
  for (int i = 0; i < 4; ++i)
    a[i] = *(const short8*)&as[(wr * 64 + i * 16 + c0) * 32 + c1 * 8];
#pragma unroll
  for (int j = 0; j < 4; ++j)
    b[j] = *(const short8*)&bs[(wc * 64 + j * 16 + c0) * 32 + c1 * 8];
#pragma unroll
  for (int i = 0; i < 4; ++i)
#pragma unroll
    for (int j = 0; j < 4; ++j)
      acc[i][j] = __builtin_amdgcn_mfma_f32_16x16x32_bf16(a[i], b[j], acc[i][j], 0, 0, 0);
}

#define GEMM_STAGE(BUF, K0) do {                                              \
    const uint16_t* ga = A + (size_t)(m0 + srow) * K + (K0) + scol;           \
    load_lds_16B(ga, &As[(BUF) * 4096 + t * 8]);                              \
    load_lds_16B(ga + (size_t)64 * K, &As[(BUF) * 4096 + 2048 + t * 8]);      \
    const uint16_t* gb = Bm + (size_t)(n0 + srow) * K + (K0) + scol;          \
    load_lds_16B(gb, &Bs[(BUF) * 4096 + t * 8]);                              \
    load_lds_16B(gb + (size_t)64 * K, &Bs[(BUF) * 4096 + 2048 + t * 8]);      \
  } while (0)

// ---------------- plain GEMM (bt) for the output projection ----------------
__global__ __launch_bounds__(256) void gemm_bt(const uint16_t* __restrict__ A,
                                               const uint16_t* __restrict__ Bm,
                                               float* __restrict__ C,
                                               int M, int N, int K) {
  __shared__ uint16_t As[3 * 4096];
  __shared__ uint16_t Bs[3 * 4096];
  const int m0 = blockIdx.x * 128;
  const int n0 = blockIdx.y * 128;
  const int t = threadIdx.x;
  const int lane = t & 63;
  const int w = t >> 6;
  const int wr = w >> 1, wc = w & 1;
  const int srow = t >> 2;
  const int scol = (t & 3) * 8;
  const int c0 = lane & 15, c1 = lane >> 4;

  floatx4 acc[4][4];
#pragma unroll
  for (int i = 0; i < 4; ++i)
#pragma unroll
    for (int j = 0; j < 4; ++j) acc[i][j] = (floatx4){0.f, 0.f, 0.f, 0.f};

  const int nk = K >> 5;
  GEMM_STAGE(0, 0);
  GEMM_STAGE(1, 32);
#pragma unroll 1
  for (int ki = 0; ki < nk - 1; ++ki) {
    WAIT_BAR(4);
    if (ki + 2 < nk) GEMM_STAGE((ki + 2) % 3, (ki + 2) * 32);
    gemm_step(&As[(ki % 3) * 4096], &Bs[(ki % 3) * 4096], wr, wc, c0, c1, acc);
  }
  WAIT_BAR(0);
  gemm_step(&As[((nk - 1) % 3) * 4096], &Bs[((nk - 1) % 3) * 4096], wr, wc, c0, c1, acc);

#pragma unroll
  for (int i = 0; i < 4; ++i)
#pragma unroll
    for (int j = 0; j < 4; ++j) {
      int row = m0 + wr * 64 + i * 16 + c1 * 4;
      int col = n0 + wc * 64 + j * 16 + c0;
      float* cp = C + (size_t)row * N + col;
#pragma unroll
      for (int r = 0; r < 4; ++r) cp[(size_t)r * N] = acc[i][j][r];
    }
}

// ---------------- fused QKV GEMM: epilogue applies RoPE + layout -----------
__global__ __launch_bounds__(256) void gemm_qkv_rope(const uint16_t* __restrict__ A,
                                                     const uint16_t* __restrict__ Bm,
                                                     const float* __restrict__ cosT,
                                                     const float* __restrict__ sinT,
                                                     uint16_t* __restrict__ qr,
                                                     uint16_t* __restrict__ kr,
                                                     uint16_t* __restrict__ vT) {
  constexpr int K = DDIM;
  __shared__ uint16_t As[3 * 4096];
  __shared__ uint16_t Bs[3 * 4096];
  const int m0 = blockIdx.x * 128;
  const int n0 = blockIdx.y * 128;
  const int t = threadIdx.x;
  const int lane = t & 63;
  const int w = t >> 6;
  const int wr = w >> 1, wc = w & 1;
  const int srow = t >> 2;
  const int scol = (t & 3) * 8;
  const int c0 = lane & 15, c1 = lane >> 4;

  floatx4 acc[4][4];
#pragma unroll
  for (int i = 0; i < 4; ++i)
#pragma unroll
    for (int j = 0; j < 4; ++j) acc[i][j] = (floatx4){0.f, 0.f, 0.f, 0.f};

  const int nk = K >> 5;  // 32
  GEMM_STAGE(0, 0);
  GEMM_STAGE(1, 32);
#pragma unroll 1
  for (int ki = 0; ki < nk - 1; ++ki) {
    WAIT_BAR(4);
    if (ki + 2 < nk) GEMM_STAGE((ki + 2) % 3, (ki + 2) * 32);
    gemm_step(&As[(ki % 3) * 4096], &Bs[(ki % 3) * 4096], wr, wc, c0, c1, acc);
  }
  WAIT_BAR(0);
  gemm_step(&As[((nk - 1) % 3) * 4096], &Bs[((nk - 1) % 3) * 4096], wr, wc, c0, c1, acc);

  // ---- epilogue: q/k rope'd, v transposed ----
#pragma unroll
  for (int j = 0; j < 4; ++j) {
    const int col = n0 + wc * 64 + j * 16 + c0;   // 0..3071
    const int sec = col >> 10;                    // 0=q 1=k 2=v
    const int e = col & 1023;
    const int h = e >> 6, dh = e & 63;
#pragma unroll
    for (int i = 0; i < 4; ++i) {
      const int row = m0 + wr * 64 + i * 16 + c1 * 4;  // b*L + l
      const int bb = row >> 11;
      const int l = row & 2047;
      if (sec == 2) {
        uint16_t* vp = vT + ((size_t)((bb * HDIM + h) * DH + dh)) * LDIM + l;
#pragma unroll
        for (int r = 0; r < 4; ++r) vp[r] = f2b(acc[i][j][r]);
      } else {
        const float sgn = (dh < 32) ? -1.f : 1.f;
        const float sc = (sec == 0) ? QSCALE : 1.f;
        uint16_t* dp = (sec == 0 ? qr : kr) + ((size_t)((bb * HDIM + h) * LDIM + l)) * DH + dh;
        const int fi = l * 32 + (dh & 31);
#pragma unroll
        for (int r = 0; r < 4; ++r) {
          float cv = cosT[fi + r * 32];
          float sv = sinT[fi + r * 32];
          float o = (acc[i][j][r] * cv + sgn * acc[i][j ^ 2][r] * sv) * sc;
          dp[(size_t)r * DH] = f2b(o);
        }
      }
    }
  }
}

// ---------------- flash attention, 32x32 MFMA, P in registers (T12) --------
// grid 512 (XCD-chunk-swizzled 1D), 256 threads = 4 waves, each wave 32 q-rows.
// S^T = mfma32(K, Q): lane holds S[q=lane&31][kv=(r&3)+8*(r>>2)+4*hi].
// Softmax lane-local; cross-half reductions via __shfl_xor(.,32).
// P redistributed to the PV B-fragment layout IN REGISTERS via
// cvt_pk + permlane32_swap (pairing = the guide's verified §B recipe):
//   w0=cvtpk(e0,e1) [kv 4hi+0,1]  swapped with  w2=cvtpk(e4,e5) [kv 8+4hi+0,1]
// giving frag dwords [kv(8hi+0,1),(8hi+2,3),(8hi+4,5),(8hi+6,7)] per chunk.
// O^T = mfma32(V^T, P^T). K,V triple-buffered swizzled LDS, counted vmcnt.

__device__ __forceinline__ void attn_phase(
    const uint16_t* __restrict__ kt, const uint16_t* __restrict__ vt,
    const int (&off)[2][4], const short8 (&qb)[4],
    float& m, float& lsum, floatx16& acc0, floatx16& acc1) {
  // ---- QK^T: two 32x32 S-tiles (kv 0-31, 32-63) ----
  floatx16 s0 = (floatx16){0.f,0.f,0.f,0.f,0.f,0.f,0.f,0.f,0.f,0.f,0.f,0.f,0.f,0.f,0.f,0.f};
  floatx16 s1 = s0;
  __builtin_amdgcn_s_setprio(1);
#pragma unroll
  for (int c = 0; c < 4; ++c) {
    short8 ka = *(const short8*)(kt + off[0][c]);
    s0 = __builtin_amdgcn_mfma_f32_32x32x16_bf16(ka, qb[c], s0, 0, 0, 0);
  }
#pragma unroll
  for (int c = 0; c < 4; ++c) {
    short8 ka = *(const short8*)(kt + off[1][c]);
    s1 = __builtin_amdgcn_mfma_f32_32x32x16_bf16(ka, qb[c], s1, 0, 0, 0);
  }
  __builtin_amdgcn_s_setprio(0);

  // ---- row max over 32 regs (q lane-local), then cross-half combine ----
  float x0 = max3f(s0[0], s0[1], s0[2]);
  float x1 = max3f(s0[3], s0[4], s0[5]);
  float x2 = max3f(s0[6], s0[7], s0[8]);
  float x3 = max3f(s0[9], s0[10], s0[11]);
  float x4 = max3f(s0[12], s0[13], s0[14]);
  float x5 = max3f(s0[15], s1[0], s1[1]);
  float x6 = max3f(s1[2], s1[3], s1[4]);
  float x7 = max3f(s1[5], s1[6], s1[7]);
  float x8 = max3f(s1[8], s1[9], s1[10]);
  float x9 = max3f(s1[11], s1[12], s1[13]);
  float xa = fmaxf(s1[14], s1[15]);
  float y0 = max3f(x0, x1, x2);
  float y1 = max3f(x3, x4, x5);
  float y2 = max3f(x6, x7, x8);
  float y3 = fmaxf(x9, xa);
  float tmax = fmaxf(max3f(y0, y1, y2), y3);
  tmax = fmaxf(tmax, __shfl_xor(tmax, 32));

  // ---- defer-max rescale (THR=8, log2 domain) ----
  if (__any(tmax > m + 8.f)) {
    float mn = fmaxf(m, tmax);
    float scl = __builtin_amdgcn_exp2f(m - mn);
    lsum *= scl;
#pragma unroll
    for (int r = 0; r < 16; ++r) { acc0[r] *= scl; acc1[r] *= scl; }
    m = mn;
  }

  // ---- exp2 + sum ----
  float e[32];
#pragma unroll
  for (int r = 0; r < 16; ++r) e[r] = __builtin_amdgcn_exp2f(s0[r] - m);
#pragma unroll
  for (int r = 0; r < 16; ++r) e[16 + r] = __builtin_amdgcn_exp2f(s1[r] - m);
  float ts0 = 0.f, ts1 = 0.f, ts2 = 0.f, ts3 = 0.f;
#pragma unroll
  for (int r = 0; r < 8; ++r) {
    ts0 += e[r]; ts1 += e[8 + r]; ts2 += e[16 + r]; ts3 += e[24 + r];
  }
  lsum += (ts0 + ts1) + (ts2 + ts3);

  // ---- pack + in-register redistribution to PV B-fragments ----
  uint32_t w0 = cvtpk(e[0], e[1]),   w1 = cvtpk(e[2], e[3]);
  uint32_t w2 = cvtpk(e[4], e[5]),   w3 = cvtpk(e[6], e[7]);
  uint32_t w4 = cvtpk(e[8], e[9]),   w5 = cvtpk(e[10], e[11]);
  uint32_t w6 = cvtpk(e[12], e[13]), w7 = cvtpk(e[14], e[15]);
  uint32_t w8 = cvtpk(e[16], e[17]), w9 = cvtpk(e[18], e[19]);
  uint32_t wa = cvtpk(e[20], e[21]), wb = cvtpk(e[22], e[23]);
  uint32_t wc_ = cvtpk(e[24], e[25]), wd = cvtpk(e[26], e[27]);
  uint32_t we = cvtpk(e[28], e[29]), wf = cvtpk(e[30], e[31]);
  PLSWAP(w0, w2);  PLSWAP(w1, w3);
  PLSWAP(w4, w6);  PLSWAP(w5, w7);
  PLSWAP(w8, wa);  PLSWAP(w9, wb);
  PLSWAP(wc_, we); PLSWAP(wd, wf);
  I4S8 pf0, pf1, pf2, pf3;
  pf0.i = (intx4){(int)w0, (int)w1, (int)w2, (int)w3};     // kv  0-15
  pf1.i = (intx4){(int)w4, (int)w5, (int)w6, (int)w7};     // kv 16-31
  pf2.i = (intx4){(int)w8, (int)w9, (int)wa, (int)wb};     // kv 32-47
  pf3.i = (intx4){(int)wc_, (int)wd, (int)we, (int)wf};    // kv 48-63

  // ---- O^T += V^T . P^T ----
  __builtin_amdgcn_s_setprio(1);
#pragma unroll
  for (int d = 0; d < 2; ++d) {
    floatx16& ac = d ? acc1 : acc0;
    ac = __builtin_amdgcn_mfma_f32_32x32x16_bf16(*(const short8*)(vt + off[d][0]), pf0.s, ac, 0, 0, 0);
    ac = __builtin_amdgcn_mfma_f32_32x32x16_bf16(*(const short8*)(vt + off[d][1]), pf1.s, ac, 0, 0, 0);
    ac = __builtin_amdgcn_mfma_f32_32x32x16_bf16(*(const short8*)(vt + off[d][2]), pf2.s, ac, 0, 0, 0);
    ac = __builtin_amdgcn_mfma_f32_32x32x16_bf16(*(const short8*)(vt + off[d][3]), pf3.s, ac, 0, 0, 0);
  }
  __builtin_amdgcn_s_setprio(0);
}

__global__ __launch_bounds__(256) void attn(const uint16_t* __restrict__ qr,
                                            const uint16_t* __restrict__ kr,
                                            const uint16_t* __restrict__ vT,
                                            uint16_t* __restrict__ out) {
  __shared__ uint16_t KsA[3 * 4096];
  __shared__ uint16_t VsA[3 * 4096];
  const int t = threadIdx.x, lane = t & 63, w = t >> 6;
  const int l31 = lane & 31, hi = lane >> 5;

  // XCD-chunk swizzle (512 % 8 == 0 -> bijective): blocks of one head
  // stay on one XCD's L2.
  const int id = blockIdx.x;
  const int sw = (id & 7) * 64 + (id >> 3);
  const int bx = sw & 15;            // L-tile
  const int h = (sw >> 4) & 15;
  const int b = sw >> 8;

  const int bh = b * HDIM + h;
  const uint16_t* Qb = qr + (size_t)bh * LDIM * DH;
  const char* Kp = (const char*)(kr + (size_t)bh * LDIM * DH);
  const char* Vp = (const char*)(vT + (size_t)bh * DH * LDIM);

  // staging geometry
  const int srow = t >> 3;
  const int scsw = ((t & 7) * 16) ^ ((srow & 7) << 4);
  const char* kgs = Kp + (size_t)srow * 128 + scsw;
  const char* vgs = Vp + (size_t)srow * (LDIM * 2) + scsw;

#define STAGE(BUF, N) do {                                                     \
    uint16_t* kd = &KsA[(BUF) * 4096];                                         \
    uint16_t* vd = &VsA[(BUF) * 4096];                                         \
    load_lds_16B((const uint16_t*)(kgs + (size_t)(N) * 8192), &kd[t * 8]);     \
    load_lds_16B((const uint16_t*)(kgs + (size_t)(N) * 8192 + 4096), &kd[2048 + t * 8]); \
    load_lds_16B((const uint16_t*)(vgs + (size_t)(N) * 128), &vd[t * 8]);      \
    load_lds_16B((const uint16_t*)(vgs + (size_t)(N) * 128 + 2 * 32 * LDIM), &vd[2048 + t * 8]); \
  } while (0)

  // Q B-fragments: lane holds Q[q0+l31][c*16 + hi*8 + j]
  const int q0 = bx * 128 + w * 32;
  short8 qb[4];
#pragma unroll
  for (int c = 0; c < 4; ++c)
    qb[c] = *(const short8*)&Qb[(size_t)(q0 + l31) * DH + c * 16 + hi * 8];

  // LDS fragment offsets (elements): row-block x, k-chunk c (shared K/V)
  const int swz = (l31 & 7) << 4;
  int off[2][4];
#pragma unroll
  for (int x = 0; x < 2; ++x)
#pragma unroll
    for (int c = 0; c < 4; ++c)
      off[x][c] = (x * 32 + l31) * 64 + (((c * 32 + hi * 16) ^ swz) >> 1);

  float m = -1e30f, lsum = 0.f;
  floatx16 acc0 = (floatx16){0.f,0.f,0.f,0.f,0.f,0.f,0.f,0.f,0.f,0.f,0.f,0.f,0.f,0.f,0.f,0.f};
  floatx16 acc1 = acc0;

  // triple-buffered pipeline: loads issued 2 tiles ahead, counted vmcnt
  STAGE(0, 0);
  STAGE(1, 1);
#pragma unroll 1
  for (int n = 0; n < 31; ++n) {
    WAIT_BAR(4);
    if (n + 2 < 32) STAGE((n + 2) % 3, n + 2);
    attn_phase(&KsA[(n % 3) * 4096], &VsA[(n % 3) * 4096], off, qb,
               m, lsum, acc0, acc1);
  }
  WAIT_BAR(0);
  attn_phase(&KsA[(31 % 3) * 4096], &VsA[(31 % 3) * 4096], off, qb,
             m, lsum, acc0, acc1);
#undef STAGE

  // ---- finalize: cross-half lsum combine, normalize, store ----
  float ltot = lsum + __shfl_xor(lsum, 32);
  float inv = 1.f / ltot;
  size_t orow = (size_t)(b * LDIM) + bx * 128 + w * 32 + l31;
  uint16_t* op = out + orow * DDIM + h * DH;
#pragma unroll
  for (int g = 0; g < 4; ++g) {
    *(uint2*)&op[8 * g + 4 * hi] =
        make_uint2(cvtpk(acc0[4 * g] * inv, acc0[4 * g + 1] * inv),
                   cvtpk(acc0[4 * g + 2] * inv, acc0[4 * g + 3] * inv));
    *(uint2*)&op[32 + 8 * g + 4 * hi] =
        make_uint2(cvtpk(acc1[4 * g] * inv, acc1[4 * g + 1] * inv),
                   cvtpk(acc1[4 * g + 2] * inv, acc1[4 * g + 3] * inv));
  }
}

// ---------------- workspace layout -----------------------------------------
static constexpr size_t OFF_XB    = 0;                   // 8 MB bf16 x
static constexpr size_t OFF_WQKVB = (size_t)8 << 20;     // 6 MB
static constexpr size_t OFF_WOUTB = (size_t)14 << 20;    // 2 MB
static constexpr size_t OFF_QR    = (size_t)16 << 20;    // 8 MB
static constexpr size_t OFF_KR    = (size_t)24 << 20;    // 8 MB
static constexpr size_t OFF_VT    = (size_t)32 << 20;    // 8 MB
static constexpr size_t OFF_AO    = (size_t)40 << 20;    // 8 MB
static constexpr size_t OFF_COS   = (size_t)48 << 20;    // 256 KB
static constexpr size_t OFF_SIN   = OFF_COS + ((size_t)256 << 10);

extern "C" void kernel_launch(void* const* d_in, const int* in_sizes, int n_in,
                              void* d_out, int out_size, void* d_ws, size_t ws_size,
                              hipStream_t stream) {
  const float* x     = (const float*)d_in[0];
  const float* w_qkv = (const float*)d_in[1];
  const float* w_out = (const float*)d_in[2];
  float* out = (float*)d_out;
  char* ws = (char*)d_ws;

  uint16_t* xb    = (uint16_t*)(ws + OFF_XB);
  uint16_t* wqkvb = (uint16_t*)(ws + OFF_WQKVB);
  uint16_t* woutb = (uint16_t*)(ws + OFF_WOUTB);
  uint16_t* qr    = (uint16_t*)(ws + OFF_QR);
  uint16_t* kr    = (uint16_t*)(ws + OFF_KR);
  uint16_t* vT    = (uint16_t*)(ws + OFF_VT);
  uint16_t* ao    = (uint16_t*)(ws + OFF_AO);
  float*    cosT  = (float*)(ws + OFF_COS);
  float*    sinT  = (float*)(ws + OFF_SIN);

  // fused converts + rope table (one launch)
  prep<<<8448, 256, 0, stream>>>(x, w_qkv, w_out, xb, wqkvb, woutb, cosT, sinT);

  // fused QKV projection + RoPE + V-transpose
  gemm_qkv_rope<<<dim3(ML / 128, 3 * DDIM / 128), 256, 0, stream>>>(xb, wqkvb, cosT, sinT, qr, kr, vT);

  // attention (1D swizzled grid)
  attn<<<512, 256, 0, stream>>>(qr, kr, vT, ao);

  // output projection
  gemm_bt<<<dim3(ML / 128, DDIM / 128), 256, 0, stream>>>(ao, woutb, out, ML, DDIM, DDIM);
}

// Round 10
// 121.788 us; speedup vs baseline: 2.6623x; 1.0089x over previous
//
#include <hip/hip_runtime.h>
#include <hip/hip_bf16.h>
#include <stdint.h>

// ---------------------------------------------------------------------------
// RoPE self-attention, B=2 L=2048 D=1024 H=16 Dh=64, f32 in/out, bf16 MFMA core
// ---------------------------------------------------------------------------

typedef __attribute__((ext_vector_type(8))) short short8;
typedef __attribute__((ext_vector_type(4))) float floatx4;
typedef __attribute__((ext_vector_type(16))) float floatx16;
typedef __attribute__((ext_vector_type(4))) int intx4;

#define BDIM 2
#define LDIM 2048
#define DDIM 1024
#define HDIM 16
#define DH 64
#define ML (BDIM * LDIM)   // 4096 rows

// log2(e) * (1/sqrt(Dh)) folded into Q at the producer -> attn softmax runs
// in exp2 domain with no per-element scaling.
#define QSCALE 0.18033688011112042f

// f32 -> bf16 round-to-nearest-even
__device__ __forceinline__ uint16_t f2b(float x) {
  uint32_t b = __float_as_uint(x);
  b += 0x7FFFu + ((b >> 16) & 1u);
  return (uint16_t)(b >> 16);
}

__device__ __forceinline__ uint32_t pack2(float a, float b) {
  return (uint32_t)f2b(a) | ((uint32_t)f2b(b) << 16);
}

// packed f32x2 -> bf16x2 in one instruction (RNE)
__device__ __forceinline__ uint32_t cvtpk(float lo, float hi) {
  uint32_t r;
  asm("v_cvt_pk_bf16_f32 %0, %1, %2" : "=v"(r) : "v"(lo), "v"(hi));
  return r;
}

// exchange a.upper32lanes <-> b.lower32lanes (HW-verified pairing, round 9)
#define PLSWAP(a, b) asm("v_permlane32_swap_b32 %0, %1" : "+v"(a), "+v"(b))

__device__ __forceinline__ float max3f(float a, float b, float c) {
  return fmaxf(fmaxf(a, b), c);
}

__device__ __forceinline__ void load_lds_16B(const uint16_t* g, uint16_t* l) {
  __builtin_amdgcn_global_load_lds(
      (const __attribute__((address_space(1))) void*)g,
      (__attribute__((address_space(3))) void*)l, 16, 0, 0);
}

// counted-vmcnt barrier pair (T4), fenced (rule #18/#21): bare s_barrier is
// NOT a compiler memory fence; sched_barrier(0) pins (no instructions).
#define WAIT_BAR(N) do {                                         \
    asm volatile("s_waitcnt vmcnt(" #N ")" ::: "memory");        \
    __builtin_amdgcn_sched_barrier(0);                           \
    __builtin_amdgcn_s_barrier();                                \
    asm volatile("" ::: "memory");                               \
    __builtin_amdgcn_sched_barrier(0);                           \
  } while (0)

union I4S8 { intx4 i; short8 s; };

// ---------------- fused prep: 3 converts + rope table, one launch ----------
__global__ void prep(const float* __restrict__ x, const float* __restrict__ wqkv,
                     const float* __restrict__ wout,
                     uint16_t* __restrict__ xb, uint16_t* __restrict__ wqkvb,
                     uint16_t* __restrict__ woutb,
                     float* __restrict__ cosT, float* __restrict__ sinT) {
  const int N0 = ML * DDIM / 4;           // 1048576
  const int N1 = 3 * DDIM * DDIM / 4;     // 786432
  const int N2 = DDIM * DDIM / 4;         // 262144
  int id = blockIdx.x * 256 + threadIdx.x;
  if (id < N0) {
    float4 v = ((const float4*)x)[id];
    ((uint2*)xb)[id] = make_uint2(pack2(v.x, v.y), pack2(v.z, v.w));
  } else if (id < N0 + N1) {
    int i = id - N0;
    float4 v = ((const float4*)wqkv)[i];
    ((uint2*)wqkvb)[i] = make_uint2(pack2(v.x, v.y), pack2(v.z, v.w));
  } else if (id < N0 + N1 + N2) {
    int i = id - N0 - N1;
    float4 v = ((const float4*)wout)[i];
    ((uint2*)woutb)[i] = make_uint2(pack2(v.x, v.y), pack2(v.z, v.w));
  } else {
    int i = id - N0 - N1 - N2;            // 0..65535 = L*32
    int l = i >> 5, f = i & 31;
    float invf = exp2f(-(float)f * (13.287712379549449f / 32.f));
    float ang = (float)l * invf;
    cosT[i] = cosf(ang);
    sinT[i] = sinf(ang);
  }
}

// ---------------- GEMM compute step (shared by both GEMMs) -----------------
__device__ __forceinline__ void gemm_step(const uint16_t* __restrict__ as,
                                          const uint16_t* __restrict__ bs,
                                          int wr, int wc, int c0, int c1,
                                          floatx4 (&acc)[4][4]) {
  short8 a[4], b[4];
#pragma unroll
  for (int i = 0; i < 4; ++i)
    a[i] = *(const short8*)&as[(wr * 64 + i * 16 + c0) * 32 + c1 * 8];
#pragma unroll
  for (int j = 0; j < 4; ++j)
    b[j] = *(const short8*)&bs[(wc * 64 + j * 16 + c0) * 32 + c1 * 8];
#pragma unroll
  for (int i = 0; i < 4; ++i)
#pragma unroll
    for (int j = 0; j < 4; ++j)
      acc[i][j] = __builtin_amdgcn_mfma_f32_16x16x32_bf16(a[i], b[j], acc[i][j], 0, 0, 0);
}

#define GEMM_STAGE(BUF, K0) do {                                              \
    const uint16_t* ga = A + (size_t)(m0 + srow) * K + (K0) + scol;           \
    load_lds_16B(ga, &As[(BUF) * 4096 + t * 8]);                              \
    load_lds_16B(ga + (size_t)64 * K, &As[(BUF) * 4096 + 2048 + t * 8]);      \
    const uint16_t* gb = Bm + (size_t)(n0 + srow) * K + (K0) + scol;          \
    load_lds_16B(gb, &Bs[(BUF) * 4096 + t * 8]);                              \
    load_lds_16B(gb + (size_t)64 * K, &Bs[(BUF) * 4096 + 2048 + t * 8]);      \
  } while (0)

// ---------------- plain GEMM (bt) for the output projection ----------------
__global__ __launch_bounds__(256) void gemm_bt(const uint16_t* __restrict__ A,
                                               const uint16_t* __restrict__ Bm,
                                               float* __restrict__ C,
                                               int M, int N, int K) {
  __shared__ uint16_t As[3 * 4096];
  __shared__ uint16_t Bs[3 * 4096];
  const int m0 = blockIdx.x * 128;
  const int n0 = blockIdx.y * 128;
  const int t = threadIdx.x;
  const int lane = t & 63;
  const int w = t >> 6;
  const int wr = w >> 1, wc = w & 1;
  const int srow = t >> 2;
  const int scol = (t & 3) * 8;
  const int c0 = lane & 15, c1 = lane >> 4;

  floatx4 acc[4][4];
#pragma unroll
  for (int i = 0; i < 4; ++i)
#pragma unroll
    for (int j = 0; j < 4; ++j) acc[i][j] = (floatx4){0.f, 0.f, 0.f, 0.f};

  const int nk = K >> 5;
  GEMM_STAGE(0, 0);
  GEMM_STAGE(1, 32);
#pragma unroll 1
  for (int ki = 0; ki < nk - 1; ++ki) {
    WAIT_BAR(4);
    if (ki + 2 < nk) GEMM_STAGE((ki + 2) % 3, (ki + 2) * 32);
    gemm_step(&As[(ki % 3) * 4096], &Bs[(ki % 3) * 4096], wr, wc, c0, c1, acc);
  }
  WAIT_BAR(0);
  gemm_step(&As[((nk - 1) % 3) * 4096], &Bs[((nk - 1) % 3) * 4096], wr, wc, c0, c1, acc);

#pragma unroll
  for (int i = 0; i < 4; ++i)
#pragma unroll
    for (int j = 0; j < 4; ++j) {
      int row = m0 + wr * 64 + i * 16 + c1 * 4;
      int col = n0 + wc * 64 + j * 16 + c0;
      float* cp = C + (size_t)row * N + col;
#pragma unroll
      for (int r = 0; r < 4; ++r) cp[(size_t)r * N] = acc[i][j][r];
    }
}

// ---------------- fused QKV GEMM: epilogue applies RoPE + layout -----------
__global__ __launch_bounds__(256) void gemm_qkv_rope(const uint16_t* __restrict__ A,
                                                     const uint16_t* __restrict__ Bm,
                                                     const float* __restrict__ cosT,
                                                     const float* __restrict__ sinT,
                                                     uint16_t* __restrict__ qr,
                                                     uint16_t* __restrict__ kr,
                                                     uint16_t* __restrict__ vT) {
  constexpr int K = DDIM;
  __shared__ uint16_t As[3 * 4096];
  __shared__ uint16_t Bs[3 * 4096];
  const int m0 = blockIdx.x * 128;
  const int n0 = blockIdx.y * 128;
  const int t = threadIdx.x;
  const int lane = t & 63;
  const int w = t >> 6;
  const int wr = w >> 1, wc = w & 1;
  const int srow = t >> 2;
  const int scol = (t & 3) * 8;
  const int c0 = lane & 15, c1 = lane >> 4;

  floatx4 acc[4][4];
#pragma unroll
  for (int i = 0; i < 4; ++i)
#pragma unroll
    for (int j = 0; j < 4; ++j) acc[i][j] = (floatx4){0.f, 0.f, 0.f, 0.f};

  const int nk = K >> 5;  // 32
  GEMM_STAGE(0, 0);
  GEMM_STAGE(1, 32);
#pragma unroll 1
  for (int ki = 0; ki < nk - 1; ++ki) {
    WAIT_BAR(4);
    if (ki + 2 < nk) GEMM_STAGE((ki + 2) % 3, (ki + 2) * 32);
    gemm_step(&As[(ki % 3) * 4096], &Bs[(ki % 3) * 4096], wr, wc, c0, c1, acc);
  }
  WAIT_BAR(0);
  gemm_step(&As[((nk - 1) % 3) * 4096], &Bs[((nk - 1) % 3) * 4096], wr, wc, c0, c1, acc);

  // ---- epilogue: q/k rope'd, v transposed ----
#pragma unroll
  for (int j = 0; j < 4; ++j) {
    const int col = n0 + wc * 64 + j * 16 + c0;   // 0..3071
    const int sec = col >> 10;                    // 0=q 1=k 2=v
    const int e = col & 1023;
    const int h = e >> 6, dh = e & 63;
#pragma unroll
    for (int i = 0; i < 4; ++i) {
      const int row = m0 + wr * 64 + i * 16 + c1 * 4;  // b*L + l
      const int bb = row >> 11;
      const int l = row & 2047;
      if (sec == 2) {
        uint16_t* vp = vT + ((size_t)((bb * HDIM + h) * DH + dh)) * LDIM + l;
#pragma unroll
        for (int r = 0; r < 4; ++r) vp[r] = f2b(acc[i][j][r]);
      } else {
        const float sgn = (dh < 32) ? -1.f : 1.f;
        const float sc = (sec == 0) ? QSCALE : 1.f;
        uint16_t* dp = (sec == 0 ? qr : kr) + ((size_t)((bb * HDIM + h) * LDIM + l)) * DH + dh;
        const int fi = l * 32 + (dh & 31);
#pragma unroll
        for (int r = 0; r < 4; ++r) {
          float cv = cosT[fi + r * 32];
          float sv = sinT[fi + r * 32];
          float o = (acc[i][j][r] * cv + sgn * acc[i][j ^ 2][r] * sv) * sc;
          dp[(size_t)r * DH] = f2b(o);
        }
      }
    }
  }
}

// ---------------- flash attention: 32x32 MFMA, T12 reg-P, T15 2-deep -------
// grid 512 (XCD-chunk-swizzled), 4 waves x 32 q-rows. Two live S-states
// (sA/sB, statically named per rule #20): per iter, QK(n+1)->next state is
// co-scheduled with softmax(n) (VALU) so the MFMA and VALU pipes overlap.
// 4 LDS buffers (64 KB): tile n's V outlives the STAGE(n+3) issue.

__device__ __forceinline__ void qk_phase(const uint16_t* __restrict__ kt,
                                         const int (&off)[2][4],
                                         const short8 (&qb)[4],
                                         floatx16& s0, floatx16& s1) {
  floatx16 z = (floatx16){0.f,0.f,0.f,0.f,0.f,0.f,0.f,0.f,0.f,0.f,0.f,0.f,0.f,0.f,0.f,0.f};
  s0 = z; s1 = z;
  __builtin_amdgcn_s_setprio(1);
#pragma unroll
  for (int c = 0; c < 4; ++c) {
    short8 ka = *(const short8*)(kt + off[0][c]);
    s0 = __builtin_amdgcn_mfma_f32_32x32x16_bf16(ka, qb[c], s0, 0, 0, 0);
  }
#pragma unroll
  for (int c = 0; c < 4; ++c) {
    short8 ka = *(const short8*)(kt + off[1][c]);
    s1 = __builtin_amdgcn_mfma_f32_32x32x16_bf16(ka, qb[c], s1, 0, 0, 0);
  }
  __builtin_amdgcn_s_setprio(0);
}

__device__ __forceinline__ void sm_pv(const uint16_t* __restrict__ vt,
                                      const int (&off)[2][4],
                                      floatx16& s0, floatx16& s1,
                                      float& m, float& lsum,
                                      floatx16& acc0, floatx16& acc1) {
  // ---- row max over 32 regs (q lane-local), then cross-half combine ----
  float x0 = max3f(s0[0], s0[1], s0[2]);
  float x1 = max3f(s0[3], s0[4], s0[5]);
  float x2 = max3f(s0[6], s0[7], s0[8]);
  float x3 = max3f(s0[9], s0[10], s0[11]);
  float x4 = max3f(s0[12], s0[13], s0[14]);
  float x5 = max3f(s0[15], s1[0], s1[1]);
  float x6 = max3f(s1[2], s1[3], s1[4]);
  float x7 = max3f(s1[5], s1[6], s1[7]);
  float x8 = max3f(s1[8], s1[9], s1[10]);
  float x9 = max3f(s1[11], s1[12], s1[13]);
  float xa = fmaxf(s1[14], s1[15]);
  float y0 = max3f(x0, x1, x2);
  float y1 = max3f(x3, x4, x5);
  float y2 = max3f(x6, x7, x8);
  float y3 = fmaxf(x9, xa);
  float tmax = fmaxf(max3f(y0, y1, y2), y3);
  tmax = fmaxf(tmax, __shfl_xor(tmax, 32));

  // ---- defer-max rescale (THR=8, log2 domain) ----
  if (__any(tmax > m + 8.f)) {
    float mn = fmaxf(m, tmax);
    float scl = __builtin_amdgcn_exp2f(m - mn);
    lsum *= scl;
#pragma unroll
    for (int r = 0; r < 16; ++r) { acc0[r] *= scl; acc1[r] *= scl; }
    m = mn;
  }

  // ---- exp2 + sum ----
  float e[32];
#pragma unroll
  for (int r = 0; r < 16; ++r) e[r] = __builtin_amdgcn_exp2f(s0[r] - m);
#pragma unroll
  for (int r = 0; r < 16; ++r) e[16 + r] = __builtin_amdgcn_exp2f(s1[r] - m);
  float ts0 = 0.f, ts1 = 0.f, ts2 = 0.f, ts3 = 0.f;
#pragma unroll
  for (int r = 0; r < 8; ++r) {
    ts0 += e[r]; ts1 += e[8 + r]; ts2 += e[16 + r]; ts3 += e[24 + r];
  }
  lsum += (ts0 + ts1) + (ts2 + ts3);

  // ---- pack + in-register redistribution to PV B-fragments (T12) ----
  uint32_t w0 = cvtpk(e[0], e[1]),   w1 = cvtpk(e[2], e[3]);
  uint32_t w2 = cvtpk(e[4], e[5]),   w3 = cvtpk(e[6], e[7]);
  uint32_t w4 = cvtpk(e[8], e[9]),   w5 = cvtpk(e[10], e[11]);
  uint32_t w6 = cvtpk(e[12], e[13]), w7 = cvtpk(e[14], e[15]);
  uint32_t w8 = cvtpk(e[16], e[17]), w9 = cvtpk(e[18], e[19]);
  uint32_t wa = cvtpk(e[20], e[21]), wb = cvtpk(e[22], e[23]);
  uint32_t wc_ = cvtpk(e[24], e[25]), wd = cvtpk(e[26], e[27]);
  uint32_t we = cvtpk(e[28], e[29]), wf = cvtpk(e[30], e[31]);
  PLSWAP(w0, w2);  PLSWAP(w1, w3);
  PLSWAP(w4, w6);  PLSWAP(w5, w7);
  PLSWAP(w8, wa);  PLSWAP(w9, wb);
  PLSWAP(wc_, we); PLSWAP(wd, wf);
  I4S8 pf0, pf1, pf2, pf3;
  pf0.i = (intx4){(int)w0, (int)w1, (int)w2, (int)w3};     // kv  0-15
  pf1.i = (intx4){(int)w4, (int)w5, (int)w6, (int)w7};     // kv 16-31
  pf2.i = (intx4){(int)w8, (int)w9, (int)wa, (int)wb};     // kv 32-47
  pf3.i = (intx4){(int)wc_, (int)wd, (int)we, (int)wf};    // kv 48-63

  // ---- O^T += V^T . P^T ----
  __builtin_amdgcn_s_setprio(1);
#pragma unroll
  for (int d = 0; d < 2; ++d) {
    floatx16& ac = d ? acc1 : acc0;
    ac = __builtin_amdgcn_mfma_f32_32x32x16_bf16(*(const short8*)(vt + off[d][0]), pf0.s, ac, 0, 0, 0);
    ac = __builtin_amdgcn_mfma_f32_32x32x16_bf16(*(const short8*)(vt + off[d][1]), pf1.s, ac, 0, 0, 0);
    ac = __builtin_amdgcn_mfma_f32_32x32x16_bf16(*(const short8*)(vt + off[d][2]), pf2.s, ac, 0, 0, 0);
    ac = __builtin_amdgcn_mfma_f32_32x32x16_bf16(*(const short8*)(vt + off[d][3]), pf3.s, ac, 0, 0, 0);
  }
  __builtin_amdgcn_s_setprio(0);
}

__global__ __launch_bounds__(256) void attn(const uint16_t* __restrict__ qr,
                                            const uint16_t* __restrict__ kr,
                                            const uint16_t* __restrict__ vT,
                                            uint16_t* __restrict__ out) {
  __shared__ uint16_t KsA[4 * 4096];
  __shared__ uint16_t VsA[4 * 4096];
  const int t = threadIdx.x, lane = t & 63, w = t >> 6;
  const int l31 = lane & 31, hi = lane >> 5;

  // XCD-chunk swizzle (512 % 8 == 0 -> bijective)
  const int id = blockIdx.x;
  const int sw = (id & 7) * 64 + (id >> 3);
  const int bx = sw & 15;            // L-tile
  const int h = (sw >> 4) & 15;
  const int b = sw >> 8;

  const int bh = b * HDIM + h;
  const uint16_t* Qb = qr + (size_t)bh * LDIM * DH;
  const char* Kp = (const char*)(kr + (size_t)bh * LDIM * DH);
  const char* Vp = (const char*)(vT + (size_t)bh * DH * LDIM);

  // staging geometry
  const int srow = t >> 3;
  const int scsw = ((t & 7) * 16) ^ ((srow & 7) << 4);
  const char* kgs = Kp + (size_t)srow * 128 + scsw;
  const char* vgs = Vp + (size_t)srow * (LDIM * 2) + scsw;

#define STAGE(BUF, N) do {                                                     \
    uint16_t* kd = &KsA[(BUF) * 4096];                                         \
    uint16_t* vd = &VsA[(BUF) * 4096];                                         \
    load_lds_16B((const uint16_t*)(kgs + (size_t)(N) * 8192), &kd[t * 8]);     \
    load_lds_16B((const uint16_t*)(kgs + (size_t)(N) * 8192 + 4096), &kd[2048 + t * 8]); \
    load_lds_16B((const uint16_t*)(vgs + (size_t)(N) * 128), &vd[t * 8]);      \
    load_lds_16B((const uint16_t*)(vgs + (size_t)(N) * 128 + 2 * 32 * LDIM), &vd[2048 + t * 8]); \
  } while (0)

  // Q B-fragments: lane holds Q[q0+l31][c*16 + hi*8 + j]
  const int q0 = bx * 128 + w * 32;
  short8 qb[4];
#pragma unroll
  for (int c = 0; c < 4; ++c)
    qb[c] = *(const short8*)&Qb[(size_t)(q0 + l31) * DH + c * 16 + hi * 8];

  // LDS fragment offsets (elements): row-block x, k-chunk c (shared K/V)
  const int swz = (l31 & 7) << 4;
  int off[2][4];
#pragma unroll
  for (int x = 0; x < 2; ++x)
#pragma unroll
    for (int c = 0; c < 4; ++c)
      off[x][c] = (x * 32 + l31) * 64 + (((c * 32 + hi * 16) ^ swz) >> 1);

  float m = -1e30f, lsum = 0.f;
  floatx16 acc0 = (floatx16){0.f,0.f,0.f,0.f,0.f,0.f,0.f,0.f,0.f,0.f,0.f,0.f,0.f,0.f,0.f,0.f};
  floatx16 acc1 = acc0;
  floatx16 sA0, sA1, sB0, sB1;

  // T15 pipeline: 3-tile prologue, QK one tile ahead of softmax/PV.
  STAGE(0, 0); STAGE(1, 1); STAGE(2, 2);
  WAIT_BAR(8);                       // tile 0 complete (tiles 1,2 in flight)
  qk_phase(&KsA[0], off, qb, sA0, sA1);

  // body(n): barrier ensures tile n+1 ready; stage n+3; QK(n+1) [MFMA]
  // co-scheduled with softmax(n) [VALU]; then PV(n).
#define BODY(n, CS0, CS1, NS0, NS1, WN) do {                                   \
    WAIT_BAR(WN);                                                              \
    if ((n) + 3 < 32) STAGE(((n) + 3) & 3, (n) + 3);                           \
    qk_phase(&KsA[(((n) + 1) & 3) * 4096], off, qb, NS0, NS1);                 \
    sm_pv(&VsA[((n) & 3) * 4096], off, CS0, CS1, m, lsum, acc0, acc1);         \
  } while (0)

#pragma unroll 1
  for (int n = 0; n < 30; n += 2) {
    BODY(n, sA0, sA1, sB0, sB1, 4);
    BODY(n + 1, sB0, sB1, sA0, sA1, 4);
  }
  BODY(30, sA0, sA1, sB0, sB1, 0);   // only STAGE(31) outstanding -> vmcnt(0)
  sm_pv(&VsA[3 * 4096], off, sB0, sB1, m, lsum, acc0, acc1);
#undef BODY
#undef STAGE

  // ---- finalize: cross-half lsum combine, normalize, store ----
  float ltot = lsum + __shfl_xor(lsum, 32);
  float inv = 1.f / ltot;
  size_t orow = (size_t)(b * LDIM) + bx * 128 + w * 32 + l31;
  uint16_t* op = out + orow * DDIM + h * DH;
#pragma unroll
  for (int g = 0; g < 4; ++g) {
    *(uint2*)&op[8 * g + 4 * hi] =
        make_uint2(cvtpk(acc0[4 * g] * inv, acc0[4 * g + 1] * inv),
                   cvtpk(acc0[4 * g + 2] * inv, acc0[4 * g + 3] * inv));
    *(uint2*)&op[32 + 8 * g + 4 * hi] =
        make_uint2(cvtpk(acc1[4 * g] * inv, acc1[4 * g + 1] * inv),
                   cvtpk(acc1[4 * g + 2] * inv, acc1[4 * g + 3] * inv));
  }
}

// ---------------- workspace layout -----------------------------------------
static constexpr size_t OFF_XB    = 0;                   // 8 MB bf16 x
static constexpr size_t OFF_WQKVB = (size_t)8 << 20;     // 6 MB
static constexpr size_t OFF_WOUTB = (size_t)14 << 20;    // 2 MB
static constexpr size_t OFF_QR    = (size_t)16 << 20;    // 8 MB
static constexpr size_t OFF_KR    = (size_t)24 << 20;    // 8 MB
static constexpr size_t OFF_VT    = (size_t)32 << 20;    // 8 MB
static constexpr size_t OFF_AO    = (size_t)40 << 20;    // 8 MB
static constexpr size_t OFF_COS   = (size_t)48 << 20;    // 256 KB
static constexpr size_t OFF_SIN   = OFF_COS + ((size_t)256 << 10);

extern "C" void kernel_launch(void* const* d_in, const int* in_sizes, int n_in,
                              void* d_out, int out_size, void* d_ws, size_t ws_size,
                              hipStream_t stream) {
  const float* x     = (const float*)d_in[0];
  const float* w_qkv = (const float*)d_in[1];
  const float* w_out = (const float*)d_in[2];
  float* out = (float*)d_out;
  char* ws = (char*)d_ws;

  uint16_t* xb    = (uint16_t*)(ws + OFF_XB);
  uint16_t* wqkvb = (uint16_t*)(ws + OFF_WQKVB);
  uint16_t* woutb = (uint16_t*)(ws + OFF_WOUTB);
  uint16_t* qr    = (uint16_t*)(ws + OFF_QR);
  uint16_t* kr    = (uint16_t*)(ws + OFF_KR);
  uint16_t* vT    = (uint16_t*)(ws + OFF_VT);
  uint16_t* ao    = (uint16_t*)(ws + OFF_AO);
  float*    cosT  = (float*)(ws + OFF_COS);
  float*    sinT  = (float*)(ws + OFF_SIN);

  // fused converts + rope table (one launch)
  prep<<<8448, 256, 0, stream>>>(x, w_qkv, w_out, xb, wqkvb, woutb, cosT, sinT);

  // fused QKV projection + RoPE + V-transpose
  gemm_qkv_rope<<<dim3(ML / 128, 3 * DDIM / 128), 256, 0, stream>>>(xb, wqkvb, cosT, sinT, qr, kr, vT);

  // attention (1D swizzled grid)
  attn<<<512, 256, 0, stream>>>(qr, kr, vT, ao);

  // output projection
  gemm_bt<<<dim3(ML / 128, DDIM / 128), 256, 0, stream>>>(ao, woutb, out, ML, DDIM, DDIM);
}